// Round 4
// baseline (1739.081 us; speedup 1.0000x reference)
//
#include <hip/hip_runtime.h>

#define D 64
#define TSCAN 1024

typedef unsigned int  u32;
typedef unsigned short u16;

__device__ __forceinline__ float bcastf(float v, int l) {
    return __uint_as_float(__builtin_amdgcn_readlane(__float_as_uint(v), l));
}
// fp32 -> bf16 bits, round-to-nearest-even
__device__ __forceinline__ u32 f2bf(float f) {
    u32 u = __float_as_uint(f);
    return (u + 0x7fffu + ((u >> 16) & 1u)) >> 16;
}
__device__ __forceinline__ float bflo(u32 v) { return __uint_as_float(v << 16); }
__device__ __forceinline__ float bfhi(u32 v) { return __uint_as_float(v & 0xffff0000u); }

// ---------- fp32 -> packed bf16 pairs ----------
__global__ void __launch_bounds__(256) tobf16_kernel(
    const float* __restrict__ x, u32* __restrict__ xh, int npairs)
{
    int t = blockIdx.x * blockDim.x + threadIdx.x;
    int st = gridDim.x * blockDim.x;
    for (int i = t; i < npairs; i += st) {
        float2 v = ((const float2*)x)[i];
        xh[i] = f2bf(v.x) | (f2bf(v.y) << 16);
    }
}

// ---------- CSR build ----------
__global__ void __launch_bounds__(256) hist_kernel(
    const int* __restrict__ dst, int* __restrict__ cnt, int E)
{
    int t = blockIdx.x * blockDim.x + threadIdx.x;
    int st = gridDim.x * blockDim.x;
    for (int e = t; e < E; e += st) atomicAdd(&cnt[dst[e]], 1);
}

__global__ void __launch_bounds__(TSCAN) partial_kernel(
    const int* __restrict__ cnt, int* __restrict__ partials, int n)
{
    __shared__ int red[TSCAN];
    int i = blockIdx.x * TSCAN + threadIdx.x;
    red[threadIdx.x] = (i < n) ? cnt[i] : 0;
    __syncthreads();
    for (int off = TSCAN / 2; off > 0; off >>= 1) {
        if (threadIdx.x < off) red[threadIdx.x] += red[threadIdx.x + off];
        __syncthreads();
    }
    if (threadIdx.x == 0) partials[blockIdx.x] = red[0];
}

__global__ void __launch_bounds__(128) scanp_kernel(
    const int* __restrict__ partials, int* __restrict__ blockoff, int nb)
{
    __shared__ int s[128];
    int t = threadIdx.x;
    int orig = (t < nb) ? partials[t] : 0;
    s[t] = orig;
    __syncthreads();
    for (int off = 1; off < 128; off <<= 1) {
        int v = (t >= off) ? s[t - off] : 0;
        __syncthreads();
        s[t] += v;
        __syncthreads();
    }
    if (t < nb) blockoff[t] = s[t] - orig;   // exclusive
}

__global__ void __launch_bounds__(TSCAN) rowptr_kernel(
    const int* __restrict__ cnt, const int* __restrict__ blockoff,
    int* __restrict__ rowptr, int* __restrict__ cursor, int n)
{
    __shared__ int s[TSCAN];
    int b = blockIdx.x;
    int i = b * TSCAN + threadIdx.x;
    int v = (i < n) ? cnt[i] : 0;
    s[threadIdx.x] = v;
    __syncthreads();
    for (int off = 1; off < TSCAN; off <<= 1) {
        int x = (threadIdx.x >= off) ? s[threadIdx.x - off] : 0;
        __syncthreads();
        s[threadIdx.x] += x;
        __syncthreads();
    }
    if (i < n) {
        int excl = blockoff[b] + s[threadIdx.x] - v;
        rowptr[i] = excl;
        cursor[i] = excl;
        if (i == n - 1) rowptr[n] = excl + v;
    }
}

__global__ void __launch_bounds__(256) fill_kernel(
    const int* __restrict__ src, const int* __restrict__ dst,
    int* __restrict__ cursor, int* __restrict__ adj, int E)
{
    int t = blockIdx.x * blockDim.x + threadIdx.x;
    int st = gridDim.x * blockDim.x;
    for (int e = t; e < E; e += st) {
        int p = atomicAdd(&cursor[dst[e]], 1);
        adj[p] = src[e];
    }
}

// ---------- fused SAGE layer on bf16 features ----------
// Wave per node. Gather: lanes 0-31 read row pairs for edge e, lanes 32-63 for
// edge e+1 (256B/instr, 2 edges). Adjacency pre-loaded to registers, shfl-broadcast.
// MLP: lane j owns output channel j; inputs broadcast via readlane.
template <bool HEAD>
__global__ void __launch_bounds__(512, 8) sage_kernel(
    const u16*   __restrict__ xh,      // [n, 64] bf16
    const int*   __restrict__ rowptr,  // [n+1]
    const int*   __restrict__ adj,     // [E]
    const float* __restrict__ W,       // [64, 128] row-major
    const float* __restrict__ b,       // [64]
    const float* __restrict__ Wc1,     // [32, 64]  (HEAD only)
    const float* __restrict__ bc1,     // [32]
    const float* __restrict__ Wc2,     // [2, 32]
    const float* __restrict__ bc2,     // [2]
    void*        __restrict__ out_,    // HEAD ? float[n,2] : bf16 u16[n,64]
    int n)
{
    extern __shared__ float smem[];
    float4* Wt4 = (float4*)smem;               // 8192 floats: Wt4[k4*64+j] = W[j][4k4..4k4+3]
    float*  Wt  = smem;
    float*  bs  = smem + 8192;                 // 64
    float*  wc1t = bs + 64;                    // 2048 (HEAD): wc1t[k*32+l] = Wc1[l][k]
    float*  w2s  = wc1t + 2048;                // 64
    float*  bc1s = w2s + 64;                   // 32
    float*  bc2s = bc1s + 32;                  // 2

    // dest-indexed staging: conflict-free LDS writes
    for (int d = threadIdx.x; d < 64 * 128; d += blockDim.x) {
        int k4 = d >> 8;
        int j  = (d >> 2) & 63;
        int kk = d & 3;
        Wt[d] = W[j * 128 + k4 * 4 + kk];
    }
    if (threadIdx.x < 64) bs[threadIdx.x] = b[threadIdx.x];
    if (HEAD) {
        for (int d = threadIdx.x; d < 32 * 64; d += blockDim.x) {
            int k = d >> 5, l = d & 31;
            wc1t[d] = Wc1[l * 64 + k];
        }
        if (threadIdx.x < 64) w2s[threadIdx.x] = Wc2[threadIdx.x];
        if (threadIdx.x < 32) bc1s[threadIdx.x] = bc1[threadIdx.x];
        if (threadIdx.x < 2)  bc2s[threadIdx.x] = bc2[threadIdx.x];
    }
    __syncthreads();

    const u32* xh32 = (const u32*)xh;
    int lane = threadIdx.x & 63;
    int g    = lane >> 5;          // edge-slot within pair
    int m    = lane & 31;          // feature-pair index
    int wid  = (blockIdx.x * blockDim.x + threadIdx.x) >> 6;
    int nw   = (gridDim.x * blockDim.x) >> 6;

    for (int node = wid; node < n; node += nw) {
        int ro = rowptr[node], re = rowptr[node + 1];
        int deg = re - ro;
        // adjacency window into registers (covers deg<=64; rare tail below)
        int av_idx = (ro + lane < re) ? adj[ro + lane] : 0;
        // self row (bf16 -> f32), issued early
        float xv = __uint_as_float(((u32)xh[(size_t)node * 64 + lane]) << 16);

        float accx = 0.f, accy = 0.f;
        int ilim = min(re, ro + 64);
        int i = ro;
        #pragma unroll 2
        for (; i + 8 <= ilim; i += 8) {
            int c = i - ro;
            int e0 = __shfl(av_idx, c + 0 + g, 64);
            int e1 = __shfl(av_idx, c + 2 + g, 64);
            int e2 = __shfl(av_idx, c + 4 + g, 64);
            int e3 = __shfl(av_idx, c + 6 + g, 64);
            u32 v0 = xh32[(size_t)e0 * 32 + m];
            u32 v1 = xh32[(size_t)e1 * 32 + m];
            u32 v2 = xh32[(size_t)e2 * 32 + m];
            u32 v3 = xh32[(size_t)e3 * 32 + m];
            accx += (bflo(v0) + bflo(v1)) + (bflo(v2) + bflo(v3));
            accy += (bfhi(v0) + bfhi(v1)) + (bfhi(v2) + bfhi(v3));
        }
        int t = ilim - i;
        if (t) {
            int c = i - ro, w = ilim - ro - 1;
            int c0 = min(c + 0 + g, w), c1 = min(c + 2 + g, w);
            int c2 = min(c + 4 + g, w), c3 = min(c + 6 + g, w);
            int e0 = __shfl(av_idx, c0, 64);
            int e1 = __shfl(av_idx, c1, 64);
            int e2 = __shfl(av_idx, c2, 64);
            int e3 = __shfl(av_idx, c3, 64);
            u32 v0 = xh32[(size_t)e0 * 32 + m];
            u32 v1 = xh32[(size_t)e1 * 32 + m];
            u32 v2 = xh32[(size_t)e2 * 32 + m];
            u32 v3 = xh32[(size_t)e3 * 32 + m];
            float m0 = (0 + g < t) ? 1.f : 0.f;
            float m1 = (2 + g < t) ? 1.f : 0.f;
            float m2 = (4 + g < t) ? 1.f : 0.f;
            float m3 = (6 + g < t) ? 1.f : 0.f;
            accx += bflo(v0) * m0 + bflo(v1) * m1 + bflo(v2) * m2 + bflo(v3) * m3;
            accy += bfhi(v0) * m0 + bfhi(v1) * m1 + bfhi(v2) * m2 + bfhi(v3) * m3;
        }
        for (int ii = ro + 64; ii < re; ++ii) {   // deg>64: ~never (Poisson(16))
            u32 v = xh32[(size_t)adj[ii] * 32 + m];
            if (g == 0) { accx += bflo(v); accy += bfhi(v); }
        }
        accx += __shfl_xor(accx, 32, 64);
        accy += __shfl_xor(accy, 32, 64);
        float inv = 1.0f / fmaxf((float)deg, 1.0f);
        accx *= inv; accy *= inv;   // lane p (and p+32) holds mean features {2p, 2p+1}

        // concat-linear
        float sum = bs[lane];
        #pragma unroll
        for (int k4 = 0; k4 < 16; ++k4) {         // self half, k = 4k4..4k4+3
            float4 w = Wt4[k4 * 64 + lane];
            sum = fmaf(bcastf(xv, 4 * k4 + 0), w.x, sum);
            sum = fmaf(bcastf(xv, 4 * k4 + 1), w.y, sum);
            sum = fmaf(bcastf(xv, 4 * k4 + 2), w.z, sum);
            sum = fmaf(bcastf(xv, 4 * k4 + 3), w.w, sum);
        }
        #pragma unroll
        for (int k4 = 0; k4 < 16; ++k4) {         // neighbor half
            float4 w = Wt4[(16 + k4) * 64 + lane];
            sum = fmaf(bcastf(accx, 2 * k4 + 0), w.x, sum);
            sum = fmaf(bcastf(accy, 2 * k4 + 0), w.y, sum);
            sum = fmaf(bcastf(accx, 2 * k4 + 1), w.z, sum);
            sum = fmaf(bcastf(accy, 2 * k4 + 1), w.w, sum);
        }
        float x2 = fmaxf(sum, 0.0f);   // ReLU

        if (!HEAD) {
            ((u16*)out_)[(size_t)node * 64 + lane] = (u16)f2bf(x2);
        } else {
            int l = lane & 31;
            float h = bc1s[l];
            #pragma unroll
            for (int k = 0; k < 64; ++k)
                h = fmaf(bcastf(x2, k), wc1t[k * 32 + l], h);
            h = fmaxf(h, 0.0f);
            float p0 = (lane < 32) ? h * w2s[l]      : 0.0f;
            float p1 = (lane < 32) ? h * w2s[32 + l] : 0.0f;
            #pragma unroll
            for (int off = 1; off < 64; off <<= 1) {
                p0 += __shfl_xor(p0, off, 64);
                p1 += __shfl_xor(p1, off, 64);
            }
            if (lane == 0) {
                float* outf = (float*)out_;
                outf[(size_t)node * 2 + 0] = p0 + bc2s[0];
                outf[(size_t)node * 2 + 1] = p1 + bc2s[1];
            }
        }
    }
}

extern "C" void kernel_launch(void* const* d_in, const int* in_sizes, int n_in,
                              void* d_out, int out_size, void* d_ws, size_t ws_size,
                              hipStream_t stream)
{
    const float* feat = (const float*)d_in[0];
    const int*   eidx = (const int*)d_in[1];
    const float* W1   = (const float*)d_in[2];
    const float* b1   = (const float*)d_in[3];
    const float* W2   = (const float*)d_in[4];
    const float* b2   = (const float*)d_in[5];
    const float* Wc1  = (const float*)d_in[6];
    const float* bc1  = (const float*)d_in[7];
    const float* Wc2  = (const float*)d_in[8];
    const float* bc2  = (const float*)d_in[9];

    int n = in_sizes[0] / D;    // 100000
    int E = in_sizes[1] / 2;    // 1600000
    const int* src = eidx;
    const int* dst = eidx + E;

    // workspace layout (words)
    int* cnt      = (int*)d_ws;                 // [n]
    int* partials = cnt + n;                    // [128]
    int* blockoff = partials + 128;             // [128]
    int* rowptr   = blockoff + 128;             // [n+1]
    int* cursor   = rowptr + n + 1;             // [n]
    int* adj      = cursor + n;                 // [E]
    u32* featH    = (u32*)(adj + E);            // [n*32] packed bf16 pairs
    u32* x1H      = featH + (size_t)n * 32;     // [n*32]

    int nb = (n + TSCAN - 1) / TSCAN;           // 98

    // bf16 feature table + CSR build
    tobf16_kernel<<<2048, 256, 0, stream>>>(feat, featH, n * 32);
    hipMemsetAsync(cnt, 0, (size_t)n * sizeof(int), stream);
    hist_kernel<<<6250, 256, 0, stream>>>(dst, cnt, E);
    partial_kernel<<<nb, TSCAN, 0, stream>>>(cnt, partials, n);
    scanp_kernel<<<1, 128, 0, stream>>>(partials, blockoff, nb);
    rowptr_kernel<<<nb, TSCAN, 0, stream>>>(cnt, blockoff, rowptr, cursor, n);
    fill_kernel<<<6250, 256, 0, stream>>>(src, dst, cursor, adj, E);

    // Layer 1: x1H = bf16(relu(SAGE(featH)))
    size_t lds1 = (8192 + 64) * sizeof(float);
    sage_kernel<false><<<1024, 512, lds1, stream>>>(
        (const u16*)featH, rowptr, adj, W1, b1,
        nullptr, nullptr, nullptr, nullptr, (void*)x1H, n);

    // Layer 2 + head: d_out = head(relu(SAGE(x1H)))
    size_t lds2 = (8192 + 64 + 2048 + 64 + 32 + 2) * sizeof(float);
    sage_kernel<true><<<1024, 512, lds2, stream>>>(
        (const u16*)x1H, rowptr, adj, W2, b2,
        Wc1, bc1, Wc2, bc2, d_out, n);
}

// Round 5
// 1699.078 us; speedup vs baseline: 1.0235x; 1.0235x over previous
//
#include <hip/hip_runtime.h>

#define D 64
#define TSCAN 1024

typedef unsigned int   u32;
typedef unsigned short u16;

__device__ __forceinline__ float bcastf(float v, int l) {
    return __uint_as_float(__builtin_amdgcn_readlane(__float_as_uint(v), l));
}
// fp32 -> bf16 bits, round-to-nearest-even
__device__ __forceinline__ u32 f2bf(float f) {
    u32 u = __float_as_uint(f);
    return (u + 0x7fffu + ((u >> 16) & 1u)) >> 16;
}
__device__ __forceinline__ float bf2f(u16 v) {
    return __uint_as_float(((u32)v) << 16);
}

// ---------- fp32 -> packed bf16 pairs ----------
__global__ void __launch_bounds__(256) tobf16_kernel(
    const float* __restrict__ x, u32* __restrict__ xh, int npairs)
{
    int t = blockIdx.x * blockDim.x + threadIdx.x;
    int st = gridDim.x * blockDim.x;
    for (int i = t; i < npairs; i += st) {
        float2 v = ((const float2*)x)[i];
        xh[i] = f2bf(v.x) | (f2bf(v.y) << 16);
    }
}

// ---------- CSR build ----------
__global__ void __launch_bounds__(256) hist_kernel(
    const int* __restrict__ dst, int* __restrict__ cnt, int E)
{
    int t = blockIdx.x * blockDim.x + threadIdx.x;
    int st = gridDim.x * blockDim.x;
    for (int e = t; e < E; e += st) atomicAdd(&cnt[dst[e]], 1);
}

__global__ void __launch_bounds__(TSCAN) partial_kernel(
    const int* __restrict__ cnt, int* __restrict__ partials, int n)
{
    __shared__ int red[TSCAN];
    int i = blockIdx.x * TSCAN + threadIdx.x;
    red[threadIdx.x] = (i < n) ? cnt[i] : 0;
    __syncthreads();
    for (int off = TSCAN / 2; off > 0; off >>= 1) {
        if (threadIdx.x < off) red[threadIdx.x] += red[threadIdx.x + off];
        __syncthreads();
    }
    if (threadIdx.x == 0) partials[blockIdx.x] = red[0];
}

__global__ void __launch_bounds__(128) scanp_kernel(
    const int* __restrict__ partials, int* __restrict__ blockoff, int nb)
{
    __shared__ int s[128];
    int t = threadIdx.x;
    int orig = (t < nb) ? partials[t] : 0;
    s[t] = orig;
    __syncthreads();
    for (int off = 1; off < 128; off <<= 1) {
        int v = (t >= off) ? s[t - off] : 0;
        __syncthreads();
        s[t] += v;
        __syncthreads();
    }
    if (t < nb) blockoff[t] = s[t] - orig;   // exclusive
}

__global__ void __launch_bounds__(TSCAN) rowptr_kernel(
    const int* __restrict__ cnt, const int* __restrict__ blockoff,
    int* __restrict__ rowptr, int* __restrict__ cursor, int n)
{
    __shared__ int s[TSCAN];
    int b = blockIdx.x;
    int i = b * TSCAN + threadIdx.x;
    int v = (i < n) ? cnt[i] : 0;
    s[threadIdx.x] = v;
    __syncthreads();
    for (int off = 1; off < TSCAN; off <<= 1) {
        int x = (threadIdx.x >= off) ? s[threadIdx.x - off] : 0;
        __syncthreads();
        s[threadIdx.x] += x;
        __syncthreads();
    }
    if (i < n) {
        int excl = blockoff[b] + s[threadIdx.x] - v;
        rowptr[i] = excl;
        cursor[i] = excl;
        if (i == n - 1) rowptr[n] = excl + v;
    }
}

__global__ void __launch_bounds__(256) fill_kernel(
    const int* __restrict__ src, const int* __restrict__ dst,
    int* __restrict__ cursor, int* __restrict__ adj, int E)
{
    int t = blockIdx.x * blockDim.x + threadIdx.x;
    int st = gridDim.x * blockDim.x;
    for (int e = t; e < E; e += st) {
        int p = atomicAdd(&cursor[dst[e]], 1);
        adj[p] = src[e];
    }
}

// ---------- fused SAGE layer on bf16 features ----------
// R3 structure: wave per node, lane j owns feature/output channel j.
// Gather: per-lane ushort load -> one 128B coalesced request per neighbor row.
// adj reads are wave-uniform (scalar path). No shfl in the gather.
template <bool HEAD>
__global__ void __launch_bounds__(512, 8) sage_kernel(
    const u16*   __restrict__ xh,      // [n, 64] bf16
    const int*   __restrict__ rowptr,  // [n+1]
    const int*   __restrict__ adj,     // [E]
    const float* __restrict__ W,       // [64, 128] row-major
    const float* __restrict__ b,       // [64]
    const float* __restrict__ Wc1,     // [32, 64]  (HEAD only)
    const float* __restrict__ bc1,     // [32]
    const float* __restrict__ Wc2,     // [2, 32]
    const float* __restrict__ bc2,     // [2]
    void*        __restrict__ out_,    // HEAD ? float[n,2] : bf16 u16[n,64]
    int n)
{
    extern __shared__ float smem[];
    float4* Wt4 = (float4*)smem;               // 8192 floats: Wt4[k4*64+j] = W[j][4k4..4k4+3]
    float*  Wt  = smem;
    float*  bs  = smem + 8192;                 // 64
    float*  wc1t = bs + 64;                    // 2048 (HEAD): wc1t[k*32+l] = Wc1[l][k]
    float*  w2s  = wc1t + 2048;                // 64
    float*  bc1s = w2s + 64;                   // 32
    float*  bc2s = bc1s + 32;                  // 2

    // dest-indexed staging: conflict-free LDS writes
    for (int d = threadIdx.x; d < 64 * 128; d += blockDim.x) {
        int k4 = d >> 8;
        int j  = (d >> 2) & 63;
        int kk = d & 3;
        Wt[d] = W[j * 128 + k4 * 4 + kk];
    }
    if (threadIdx.x < 64) bs[threadIdx.x] = b[threadIdx.x];
    if (HEAD) {
        for (int d = threadIdx.x; d < 32 * 64; d += blockDim.x) {
            int k = d >> 5, l = d & 31;
            wc1t[d] = Wc1[l * 64 + k];
        }
        if (threadIdx.x < 64) w2s[threadIdx.x] = Wc2[threadIdx.x];
        if (threadIdx.x < 32) bc1s[threadIdx.x] = bc1[threadIdx.x];
        if (threadIdx.x < 2)  bc2s[threadIdx.x] = bc2[threadIdx.x];
    }
    __syncthreads();

    int lane = threadIdx.x & 63;
    int wid  = (blockIdx.x * blockDim.x + threadIdx.x) >> 6;
    int nw   = (gridDim.x * blockDim.x) >> 6;
    for (int node = wid; node < n; node += nw) {
        int ro = rowptr[node], re = rowptr[node + 1];
        int deg = re - ro;
        float xv = bf2f(xh[(size_t)node * D + lane]);   // self row, early

        // gather-sum: 8 independent 128B row loads in flight, 2 accumulators
        float acc0 = 0.f, acc1 = 0.f;
        int i = ro;
        #pragma unroll 2
        for (; i + 8 <= re; i += 8) {
            int s0 = adj[i+0], s1 = adj[i+1], s2 = adj[i+2], s3 = adj[i+3];
            int s4 = adj[i+4], s5 = adj[i+5], s6 = adj[i+6], s7 = adj[i+7];
            float v0 = bf2f(xh[(size_t)s0 * D + lane]);
            float v1 = bf2f(xh[(size_t)s1 * D + lane]);
            float v2 = bf2f(xh[(size_t)s2 * D + lane]);
            float v3 = bf2f(xh[(size_t)s3 * D + lane]);
            float v4 = bf2f(xh[(size_t)s4 * D + lane]);
            float v5 = bf2f(xh[(size_t)s5 * D + lane]);
            float v6 = bf2f(xh[(size_t)s6 * D + lane]);
            float v7 = bf2f(xh[(size_t)s7 * D + lane]);
            acc0 += (v0 + v1) + (v2 + v3);
            acc1 += (v4 + v5) + (v6 + v7);
        }
        for (; i < re; ++i) acc0 += bf2f(xh[(size_t)adj[i] * D + lane]);
        float av = (acc0 + acc1) / fmaxf((float)deg, 1.0f);

        // concat-linear: sum_j = b[j] + sum_k xv_k*W[j][k] + sum_k av_k*W[j][64+k]
        float sum = bs[lane];
        #pragma unroll
        for (int k4 = 0; k4 < 16; ++k4) {
            float4 w = Wt4[k4 * 64 + lane];
            sum = fmaf(bcastf(xv, 4 * k4 + 0), w.x, sum);
            sum = fmaf(bcastf(xv, 4 * k4 + 1), w.y, sum);
            sum = fmaf(bcastf(xv, 4 * k4 + 2), w.z, sum);
            sum = fmaf(bcastf(xv, 4 * k4 + 3), w.w, sum);
        }
        #pragma unroll
        for (int k4 = 16; k4 < 32; ++k4) {
            float4 w = Wt4[k4 * 64 + lane];
            int kk = 4 * (k4 - 16);
            sum = fmaf(bcastf(av, kk + 0), w.x, sum);
            sum = fmaf(bcastf(av, kk + 1), w.y, sum);
            sum = fmaf(bcastf(av, kk + 2), w.z, sum);
            sum = fmaf(bcastf(av, kk + 3), w.w, sum);
        }
        float x2 = fmaxf(sum, 0.0f);   // ReLU

        if (!HEAD) {
            ((u16*)out_)[(size_t)node * D + lane] = (u16)f2bf(x2);
        } else {
            int l = lane & 31;
            float h = bc1s[l];
            #pragma unroll
            for (int k = 0; k < 64; ++k)
                h = fmaf(bcastf(x2, k), wc1t[k * 32 + l], h);
            h = fmaxf(h, 0.0f);
            float p0 = (lane < 32) ? h * w2s[l]      : 0.0f;
            float p1 = (lane < 32) ? h * w2s[32 + l] : 0.0f;
            #pragma unroll
            for (int off = 1; off < 64; off <<= 1) {
                p0 += __shfl_xor(p0, off, 64);
                p1 += __shfl_xor(p1, off, 64);
            }
            if (lane == 0) {
                float* outf = (float*)out_;
                outf[(size_t)node * 2 + 0] = p0 + bc2s[0];
                outf[(size_t)node * 2 + 1] = p1 + bc2s[1];
            }
        }
    }
}

extern "C" void kernel_launch(void* const* d_in, const int* in_sizes, int n_in,
                              void* d_out, int out_size, void* d_ws, size_t ws_size,
                              hipStream_t stream)
{
    const float* feat = (const float*)d_in[0];
    const int*   eidx = (const int*)d_in[1];
    const float* W1   = (const float*)d_in[2];
    const float* b1   = (const float*)d_in[3];
    const float* W2   = (const float*)d_in[4];
    const float* b2   = (const float*)d_in[5];
    const float* Wc1  = (const float*)d_in[6];
    const float* bc1  = (const float*)d_in[7];
    const float* Wc2  = (const float*)d_in[8];
    const float* bc2  = (const float*)d_in[9];

    int n = in_sizes[0] / D;    // 100000
    int E = in_sizes[1] / 2;    // 1600000
    const int* src = eidx;
    const int* dst = eidx + E;

    // workspace layout (words)
    int* cnt      = (int*)d_ws;                 // [n]
    int* partials = cnt + n;                    // [128]
    int* blockoff = partials + 128;             // [128]
    int* rowptr   = blockoff + 128;             // [n+1]
    int* cursor   = rowptr + n + 1;             // [n]
    int* adj      = cursor + n;                 // [E]
    u32* featH    = (u32*)(adj + E);            // [n*32] packed bf16 pairs
    u32* x1H      = featH + (size_t)n * 32;     // [n*32]

    int nb = (n + TSCAN - 1) / TSCAN;           // 98

    // bf16 feature table + CSR build
    tobf16_kernel<<<2048, 256, 0, stream>>>(feat, featH, n * 32);
    hipMemsetAsync(cnt, 0, (size_t)n * sizeof(int), stream);
    hist_kernel<<<6250, 256, 0, stream>>>(dst, cnt, E);
    partial_kernel<<<nb, TSCAN, 0, stream>>>(cnt, partials, n);
    scanp_kernel<<<1, 128, 0, stream>>>(partials, blockoff, nb);
    rowptr_kernel<<<nb, TSCAN, 0, stream>>>(cnt, blockoff, rowptr, cursor, n);
    fill_kernel<<<6250, 256, 0, stream>>>(src, dst, cursor, adj, E);

    // Layer 1: x1H = bf16(relu(SAGE(featH)))
    size_t lds1 = (8192 + 64) * sizeof(float);
    sage_kernel<false><<<2048, 512, lds1, stream>>>(
        (const u16*)featH, rowptr, adj, W1, b1,
        nullptr, nullptr, nullptr, nullptr, (void*)x1H, n);

    // Layer 2 + head: d_out = head(relu(SAGE(x1H)))
    size_t lds2 = (8192 + 64 + 2048 + 64 + 32 + 2) * sizeof(float);
    sage_kernel<true><<<2048, 512, lds2, stream>>>(
        (const u16*)x1H, rowptr, adj, W2, b2,
        Wc1, bc1, Wc2, bc2, d_out, n);
}

// Round 6
// 1659.115 us; speedup vs baseline: 1.0482x; 1.0241x over previous
//
#include <hip/hip_runtime.h>

#define D 64
#define TSCAN 1024

typedef unsigned int   u32;
typedef unsigned short u16;

__device__ __forceinline__ float bcastf(float v, int l) {
    return __uint_as_float(__builtin_amdgcn_readlane(__float_as_uint(v), l));
}
// fp32 -> bf16 bits, round-to-nearest-even
__device__ __forceinline__ u32 f2bf(float f) {
    u32 u = __float_as_uint(f);
    return (u + 0x7fffu + ((u >> 16) & 1u)) >> 16;
}
__device__ __forceinline__ float bflo(u32 v) { return __uint_as_float(v << 16); }
__device__ __forceinline__ float bfhi(u32 v) { return __uint_as_float(v & 0xffff0000u); }

// ---------- fp32 -> packed bf16 pairs ----------
__global__ void __launch_bounds__(256) tobf16_kernel(
    const float* __restrict__ x, u32* __restrict__ xh, int npairs)
{
    int t = blockIdx.x * blockDim.x + threadIdx.x;
    int st = gridDim.x * blockDim.x;
    for (int i = t; i < npairs; i += st) {
        float2 v = ((const float2*)x)[i];
        xh[i] = f2bf(v.x) | (f2bf(v.y) << 16);
    }
}

// ---------- CSR build ----------
__global__ void __launch_bounds__(256) hist_kernel(
    const int* __restrict__ dst, int* __restrict__ cnt, int E)
{
    int t = blockIdx.x * blockDim.x + threadIdx.x;
    int st = gridDim.x * blockDim.x;
    for (int e = t; e < E; e += st) atomicAdd(&cnt[dst[e]], 1);
}

__global__ void __launch_bounds__(TSCAN) partial_kernel(
    const int* __restrict__ cnt, int* __restrict__ partials, int n)
{
    __shared__ int red[TSCAN];
    int i = blockIdx.x * TSCAN + threadIdx.x;
    red[threadIdx.x] = (i < n) ? cnt[i] : 0;
    __syncthreads();
    for (int off = TSCAN / 2; off > 0; off >>= 1) {
        if (threadIdx.x < off) red[threadIdx.x] += red[threadIdx.x + off];
        __syncthreads();
    }
    if (threadIdx.x == 0) partials[blockIdx.x] = red[0];
}

__global__ void __launch_bounds__(128) scanp_kernel(
    const int* __restrict__ partials, int* __restrict__ blockoff, int nb)
{
    __shared__ int s[128];
    int t = threadIdx.x;
    int orig = (t < nb) ? partials[t] : 0;
    s[t] = orig;
    __syncthreads();
    for (int off = 1; off < 128; off <<= 1) {
        int v = (t >= off) ? s[t - off] : 0;
        __syncthreads();
        s[t] += v;
        __syncthreads();
    }
    if (t < nb) blockoff[t] = s[t] - orig;   // exclusive
}

__global__ void __launch_bounds__(TSCAN) rowptr_kernel(
    const int* __restrict__ cnt, const int* __restrict__ blockoff,
    int* __restrict__ rowptr, int* __restrict__ cursor, int n)
{
    __shared__ int s[TSCAN];
    int b = blockIdx.x;
    int i = b * TSCAN + threadIdx.x;
    int v = (i < n) ? cnt[i] : 0;
    s[threadIdx.x] = v;
    __syncthreads();
    for (int off = 1; off < TSCAN; off <<= 1) {
        int x = (threadIdx.x >= off) ? s[threadIdx.x - off] : 0;
        __syncthreads();
        s[threadIdx.x] += x;
        __syncthreads();
    }
    if (i < n) {
        int excl = blockoff[b] + s[threadIdx.x] - v;
        rowptr[i] = excl;
        cursor[i] = excl;
        if (i == n - 1) rowptr[n] = excl + v;
    }
}

__global__ void __launch_bounds__(256) fill_kernel(
    const int* __restrict__ src, const int* __restrict__ dst,
    int* __restrict__ cursor, int* __restrict__ adj, int E)
{
    int t = blockIdx.x * blockDim.x + threadIdx.x;
    int st = gridDim.x * blockDim.x;
    for (int e = t; e < E; e += st) {
        int p = atomicAdd(&cursor[dst[e]], 1);
        adj[p] = src[e];
    }
}

// ---------- fused SAGE layer on packed-bf16 features ----------
// Wave per node. Feature row = 32 u32 (bf16 pairs) = 128B; lane m=lane&31 loads
// dword m (halves duplicate -> same line, HW-merged). Addresses come straight
// from wave-uniform scalar adj loads. Lane m owns feature pair {2m, 2m+1}.
// MLP: lane j owns output channel j; pair values broadcast via readlane.
template <bool HEAD>
__global__ void __launch_bounds__(512, 8) sage_kernel(
    const u32*   __restrict__ xp,      // [n, 32] packed bf16 pairs
    const int*   __restrict__ rowptr,  // [n+1]
    const int*   __restrict__ adj,     // [E]
    const float* __restrict__ W,       // [64, 128] row-major
    const float* __restrict__ b,       // [64]
    const float* __restrict__ Wc1,     // [32, 64]  (HEAD only)
    const float* __restrict__ bc1,     // [32]
    const float* __restrict__ Wc2,     // [2, 32]
    const float* __restrict__ bc2,     // [2]
    void*        __restrict__ out_,    // HEAD ? float[n,2] : u32[n,32] packed
    int n)
{
    extern __shared__ float smem[];
    float4* Wt4 = (float4*)smem;               // 8192 floats: Wt4[k4*64+j] = W[j][4k4..4k4+3]
    float*  Wt  = smem;
    float*  bs  = smem + 8192;                 // 64
    float*  wc1t = bs + 64;                    // 2048 (HEAD): wc1t[k*32+l] = Wc1[l][k]
    float*  w2s  = wc1t + 2048;                // 64
    float*  bc1s = w2s + 64;                   // 32
    float*  bc2s = bc1s + 32;                  // 2

    // dest-indexed staging: conflict-free LDS writes
    for (int d = threadIdx.x; d < 64 * 128; d += blockDim.x) {
        int k4 = d >> 8;
        int j  = (d >> 2) & 63;
        int kk = d & 3;
        Wt[d] = W[j * 128 + k4 * 4 + kk];
    }
    if (threadIdx.x < 64) bs[threadIdx.x] = b[threadIdx.x];
    if (HEAD) {
        for (int d = threadIdx.x; d < 32 * 64; d += blockDim.x) {
            int k = d >> 5, l = d & 31;
            wc1t[d] = Wc1[l * 64 + k];
        }
        if (threadIdx.x < 64) w2s[threadIdx.x] = Wc2[threadIdx.x];
        if (threadIdx.x < 32) bc1s[threadIdx.x] = bc1[threadIdx.x];
        if (threadIdx.x < 2)  bc2s[threadIdx.x] = bc2[threadIdx.x];
    }
    __syncthreads();

    int lane = threadIdx.x & 63;
    int m    = lane & 31;
    int wid  = (blockIdx.x * blockDim.x + threadIdx.x) >> 6;
    int nw   = (gridDim.x * blockDim.x) >> 6;
    for (int node = wid; node < n; node += nw) {
        int ro = rowptr[node], re = rowptr[node + 1];
        int deg = re - ro;
        u32 sv = xp[(size_t)node * 32 + m];     // self row, early
        float xvx = bflo(sv), xvy = bfhi(sv);

        // gather-sum: 8 independent 128B row loads in flight
        float ax0 = 0.f, ay0 = 0.f, ax1 = 0.f, ay1 = 0.f;
        int i = ro;
        #pragma unroll 2
        for (; i + 8 <= re; i += 8) {
            int s0 = adj[i+0], s1 = adj[i+1], s2 = adj[i+2], s3 = adj[i+3];
            int s4 = adj[i+4], s5 = adj[i+5], s6 = adj[i+6], s7 = adj[i+7];
            u32 v0 = xp[(size_t)s0 * 32 + m];
            u32 v1 = xp[(size_t)s1 * 32 + m];
            u32 v2 = xp[(size_t)s2 * 32 + m];
            u32 v3 = xp[(size_t)s3 * 32 + m];
            u32 v4 = xp[(size_t)s4 * 32 + m];
            u32 v5 = xp[(size_t)s5 * 32 + m];
            u32 v6 = xp[(size_t)s6 * 32 + m];
            u32 v7 = xp[(size_t)s7 * 32 + m];
            ax0 += (bflo(v0) + bflo(v1)) + (bflo(v2) + bflo(v3));
            ay0 += (bfhi(v0) + bfhi(v1)) + (bfhi(v2) + bfhi(v3));
            ax1 += (bflo(v4) + bflo(v5)) + (bflo(v6) + bflo(v7));
            ay1 += (bfhi(v4) + bfhi(v5)) + (bfhi(v6) + bfhi(v7));
        }
        for (; i < re; ++i) {
            u32 v = xp[(size_t)adj[i] * 32 + m];
            ax0 += bflo(v); ay0 += bfhi(v);
        }
        float inv  = 1.0f / fmaxf((float)deg, 1.0f);
        float accx = (ax0 + ax1) * inv;   // mean of feature 2m
        float accy = (ay0 + ay1) * inv;   // mean of feature 2m+1

        // concat-linear: feature 4k4+{0,1,2,3} = {x@2k4, y@2k4, x@2k4+1, y@2k4+1}
        float sum = bs[lane];
        #pragma unroll
        for (int k4 = 0; k4 < 16; ++k4) {         // self half
            float4 w = Wt4[k4 * 64 + lane];
            sum = fmaf(bcastf(xvx, 2 * k4 + 0), w.x, sum);
            sum = fmaf(bcastf(xvy, 2 * k4 + 0), w.y, sum);
            sum = fmaf(bcastf(xvx, 2 * k4 + 1), w.z, sum);
            sum = fmaf(bcastf(xvy, 2 * k4 + 1), w.w, sum);
        }
        #pragma unroll
        for (int k4 = 0; k4 < 16; ++k4) {         // neighbor half
            float4 w = Wt4[(16 + k4) * 64 + lane];
            sum = fmaf(bcastf(accx, 2 * k4 + 0), w.x, sum);
            sum = fmaf(bcastf(accy, 2 * k4 + 0), w.y, sum);
            sum = fmaf(bcastf(accx, 2 * k4 + 1), w.z, sum);
            sum = fmaf(bcastf(accy, 2 * k4 + 1), w.w, sum);
        }
        float x2 = fmaxf(sum, 0.0f);   // ReLU; lane j holds output channel j

        if (!HEAD) {
            // pack pairs in-register, dword stores only (lanes 0,2,4,..)
            u32 bits = f2bf(x2);
            u32 part = (u32)__shfl_xor((int)bits, 1, 64);
            if (!(lane & 1))
                ((u32*)out_)[(size_t)node * 32 + (lane >> 1)] = bits | (part << 16);
        } else {
            int l = lane & 31;
            float h = bc1s[l];
            #pragma unroll
            for (int k = 0; k < 64; ++k)
                h = fmaf(bcastf(x2, k), wc1t[k * 32 + l], h);
            h = fmaxf(h, 0.0f);
            float p0 = (lane < 32) ? h * w2s[l]      : 0.0f;
            float p1 = (lane < 32) ? h * w2s[32 + l] : 0.0f;
            #pragma unroll
            for (int off = 1; off < 64; off <<= 1) {
                p0 += __shfl_xor(p0, off, 64);
                p1 += __shfl_xor(p1, off, 64);
            }
            if (lane == 0) {
                float* outf = (float*)out_;
                outf[(size_t)node * 2 + 0] = p0 + bc2s[0];
                outf[(size_t)node * 2 + 1] = p1 + bc2s[1];
            }
        }
    }
}

extern "C" void kernel_launch(void* const* d_in, const int* in_sizes, int n_in,
                              void* d_out, int out_size, void* d_ws, size_t ws_size,
                              hipStream_t stream)
{
    const float* feat = (const float*)d_in[0];
    const int*   eidx = (const int*)d_in[1];
    const float* W1   = (const float*)d_in[2];
    const float* b1   = (const float*)d_in[3];
    const float* W2   = (const float*)d_in[4];
    const float* b2   = (const float*)d_in[5];
    const float* Wc1  = (const float*)d_in[6];
    const float* bc1  = (const float*)d_in[7];
    const float* Wc2  = (const float*)d_in[8];
    const float* bc2  = (const float*)d_in[9];

    int n = in_sizes[0] / D;    // 100000
    int E = in_sizes[1] / 2;    // 1600000
    const int* src = eidx;
    const int* dst = eidx + E;

    // workspace layout (words)
    int* cnt      = (int*)d_ws;                 // [n]
    int* partials = cnt + n;                    // [128]
    int* blockoff = partials + 128;             // [128]
    int* rowptr   = blockoff + 128;             // [n+1]
    int* cursor   = rowptr + n + 1;             // [n]
    int* adj      = cursor + n;                 // [E]
    u32* featP    = (u32*)(adj + E);            // [n*32] packed bf16 pairs
    u32* x1P      = featP + (size_t)n * 32;     // [n*32]

    int nb = (n + TSCAN - 1) / TSCAN;           // 98

    // bf16 feature table + CSR build
    tobf16_kernel<<<2048, 256, 0, stream>>>(feat, featP, n * 32);
    hipMemsetAsync(cnt, 0, (size_t)n * sizeof(int), stream);
    hist_kernel<<<6250, 256, 0, stream>>>(dst, cnt, E);
    partial_kernel<<<nb, TSCAN, 0, stream>>>(cnt, partials, n);
    scanp_kernel<<<1, 128, 0, stream>>>(partials, blockoff, nb);
    rowptr_kernel<<<nb, TSCAN, 0, stream>>>(cnt, blockoff, rowptr, cursor, n);
    fill_kernel<<<6250, 256, 0, stream>>>(src, dst, cursor, adj, E);

    // Layer 1: x1P = packbf16(relu(SAGE(featP)))
    size_t lds1 = (8192 + 64) * sizeof(float);
    sage_kernel<false><<<1024, 512, lds1, stream>>>(
        featP, rowptr, adj, W1, b1,
        nullptr, nullptr, nullptr, nullptr, (void*)x1P, n);

    // Layer 2 + head: d_out = head(relu(SAGE(x1P)))
    size_t lds2 = (8192 + 64 + 2048 + 64 + 32 + 2) * sizeof(float);
    sage_kernel<true><<<1024, 512, lds2, stream>>>(
        x1P, rowptr, adj, W2, b2,
        Wc1, bc1, Wc2, bc2, d_out, n);
}

// Round 7
// 1621.811 us; speedup vs baseline: 1.0723x; 1.0230x over previous
//
#include <hip/hip_runtime.h>

#define D 64
#define TSCAN 1024

typedef unsigned int   u32;
typedef unsigned short u16;

__device__ __forceinline__ float bcastf(float v, int l) {
    return __uint_as_float(__builtin_amdgcn_readlane(__float_as_uint(v), l));
}
__device__ __forceinline__ u32 f2bf(float f) {
    u32 u = __float_as_uint(f);
    return (u + 0x7fffu + ((u >> 16) & 1u)) >> 16;
}
__device__ __forceinline__ float bflo(u32 v) { return __uint_as_float(v << 16); }
__device__ __forceinline__ float bfhi(u32 v) { return __uint_as_float(v & 0xffff0000u); }

// ---------- CSR build ----------
__global__ void __launch_bounds__(256) hist_kernel(
    const int* __restrict__ dst, int* __restrict__ cnt, int E)
{
    int t = blockIdx.x * blockDim.x + threadIdx.x;
    int st = gridDim.x * blockDim.x;
    for (int e = t; e < E; e += st) atomicAdd(&cnt[dst[e]], 1);
}

__global__ void __launch_bounds__(TSCAN) partial_kernel(
    const int* __restrict__ cnt, int* __restrict__ partials, int n)
{
    __shared__ int red[TSCAN];
    int i = blockIdx.x * TSCAN + threadIdx.x;
    red[threadIdx.x] = (i < n) ? cnt[i] : 0;
    __syncthreads();
    for (int off = TSCAN / 2; off > 0; off >>= 1) {
        if (threadIdx.x < off) red[threadIdx.x] += red[threadIdx.x + off];
        __syncthreads();
    }
    if (threadIdx.x == 0) partials[blockIdx.x] = red[0];
}

__global__ void __launch_bounds__(128) scanp_kernel(
    const int* __restrict__ partials, int* __restrict__ blockoff, int nb)
{
    __shared__ int s[128];
    int t = threadIdx.x;
    int orig = (t < nb) ? partials[t] : 0;
    s[t] = orig;
    __syncthreads();
    for (int off = 1; off < 128; off <<= 1) {
        int v = (t >= off) ? s[t - off] : 0;
        __syncthreads();
        s[t] += v;
        __syncthreads();
    }
    if (t < nb) blockoff[t] = s[t] - orig;   // exclusive
}

__global__ void __launch_bounds__(TSCAN) rowptr_kernel(
    const int* __restrict__ cnt, const int* __restrict__ blockoff,
    int* __restrict__ rowptr, int* __restrict__ cursor, int n)
{
    __shared__ int s[TSCAN];
    int b = blockIdx.x;
    int i = b * TSCAN + threadIdx.x;
    int v = (i < n) ? cnt[i] : 0;
    s[threadIdx.x] = v;
    __syncthreads();
    for (int off = 1; off < TSCAN; off <<= 1) {
        int x = (threadIdx.x >= off) ? s[threadIdx.x - off] : 0;
        __syncthreads();
        s[threadIdx.x] += x;
        __syncthreads();
    }
    if (i < n) {
        int excl = blockoff[b] + s[threadIdx.x] - v;
        rowptr[i] = excl;
        cursor[i] = excl;
        if (i == n - 1) rowptr[n] = excl + v;
    }
}

__global__ void __launch_bounds__(256) fill_kernel(
    const int* __restrict__ src, const int* __restrict__ dst,
    int* __restrict__ cursor, int* __restrict__ adj, int E)
{
    int t = blockIdx.x * blockDim.x + threadIdx.x;
    int st = gridDim.x * blockDim.x;
    for (int e = t; e < E; e += st) {
        int p = atomicAdd(&cursor[dst[e]], 1);
        adj[p] = src[e];
    }
}

// ---------- fused SAGE layer (R3 structure, fp32) ----------
// Wave per node; lane j owns feature/output channel j.
// LDS = exactly 32KB (W only) for !HEAD; +4KB packed-bf16 Wc1 for HEAD.
// Bias and head small weights live in per-lane registers.
template <bool HEAD>
__global__ void __launch_bounds__(512, 8) sage_kernel(
    const float* __restrict__ x,       // [n, 64]
    const int*   __restrict__ rowptr,  // [n+1]
    const int*   __restrict__ adj,     // [E]
    const float* __restrict__ W,       // [64, 128] row-major
    const float* __restrict__ b,       // [64]
    const float* __restrict__ Wc1,     // [32, 64]  (HEAD only)
    const float* __restrict__ bc1,     // [32]
    const float* __restrict__ Wc2,     // [2, 32]
    const float* __restrict__ bc2,     // [2]
    float*       __restrict__ out,     // HEAD ? [n,2] : [n,64]
    int n)
{
    extern __shared__ float smem[];
    float4* Wt4 = (float4*)smem;               // 8192 floats = 32KB: Wt4[k4*64+j] = W[j][4k4..]
    float*  Wt  = smem;
    u32*    wc1p = (u32*)(smem + 8192);        // 1024 u32 = 4KB (HEAD): packed Wc1 pairs

    // dest-indexed staging: conflict-free LDS writes
    for (int d = threadIdx.x; d < 64 * 128; d += blockDim.x) {
        int k4 = d >> 8;
        int j  = (d >> 2) & 63;
        int kk = d & 3;
        Wt[d] = W[j * 128 + k4 * 4 + kk];
    }
    if (HEAD) {
        for (int d = threadIdx.x; d < 32 * 32; d += blockDim.x) {
            int k2 = d >> 5, l = d & 31;
            wc1p[d] = f2bf(Wc1[l * 64 + 2 * k2]) | (f2bf(Wc1[l * 64 + 2 * k2 + 1]) << 16);
        }
    }
    __syncthreads();

    int lane = threadIdx.x & 63;
    int l    = lane & 31;
    float bj = b[lane];                        // bias in register (no LDS)
    float bc1r = 0.f, w2a = 0.f, w2b = 0.f, bc20 = 0.f, bc21 = 0.f;
    if (HEAD) {
        bc1r = bc1[l];
        w2a  = Wc2[l];
        w2b  = Wc2[32 + l];
        bc20 = bc2[0];
        bc21 = bc2[1];
    }

    int wid  = (blockIdx.x * blockDim.x + threadIdx.x) >> 6;
    int nw   = (gridDim.x * blockDim.x) >> 6;
    for (int node = wid; node < n; node += nw) {
        int ro = rowptr[node], re = rowptr[node + 1];
        int deg = re - ro;
        float xv = x[(size_t)node * D + lane];   // self row, early

        // gather-sum: 8 independent 256B row loads in flight, 2 accumulators
        float acc0 = 0.f, acc1 = 0.f;
        int i = ro;
        #pragma unroll 2
        for (; i + 8 <= re; i += 8) {
            int s0 = adj[i+0], s1 = adj[i+1], s2 = adj[i+2], s3 = adj[i+3];
            int s4 = adj[i+4], s5 = adj[i+5], s6 = adj[i+6], s7 = adj[i+7];
            float v0 = x[(size_t)s0 * D + lane];
            float v1 = x[(size_t)s1 * D + lane];
            float v2 = x[(size_t)s2 * D + lane];
            float v3 = x[(size_t)s3 * D + lane];
            float v4 = x[(size_t)s4 * D + lane];
            float v5 = x[(size_t)s5 * D + lane];
            float v6 = x[(size_t)s6 * D + lane];
            float v7 = x[(size_t)s7 * D + lane];
            acc0 += (v0 + v1) + (v2 + v3);
            acc1 += (v4 + v5) + (v6 + v7);
        }
        for (; i < re; ++i) acc0 += x[(size_t)adj[i] * D + lane];
        float av = (acc0 + acc1) / fmaxf((float)deg, 1.0f);

        // concat-linear: sum_j = b[j] + sum_k xv_k*W[j][k] + sum_k av_k*W[j][64+k]
        float sum = bj;
        #pragma unroll
        for (int k4 = 0; k4 < 16; ++k4) {
            float4 w = Wt4[k4 * 64 + lane];
            sum = fmaf(bcastf(xv, 4 * k4 + 0), w.x, sum);
            sum = fmaf(bcastf(xv, 4 * k4 + 1), w.y, sum);
            sum = fmaf(bcastf(xv, 4 * k4 + 2), w.z, sum);
            sum = fmaf(bcastf(xv, 4 * k4 + 3), w.w, sum);
        }
        #pragma unroll
        for (int k4 = 16; k4 < 32; ++k4) {
            float4 w = Wt4[k4 * 64 + lane];
            int kk = 4 * (k4 - 16);
            sum = fmaf(bcastf(av, kk + 0), w.x, sum);
            sum = fmaf(bcastf(av, kk + 1), w.y, sum);
            sum = fmaf(bcastf(av, kk + 2), w.z, sum);
            sum = fmaf(bcastf(av, kk + 3), w.w, sum);
        }
        float x2 = fmaxf(sum, 0.0f);   // ReLU; lane j holds output channel j

        if (!HEAD) {
            out[(size_t)node * D + lane] = x2;
        } else {
            // h[l] = relu(bc1[l] + sum_k x2_k * Wc1[l][k]); Wc1 packed bf16 in LDS
            float h = bc1r;
            #pragma unroll
            for (int k2 = 0; k2 < 32; ++k2) {
                u32 wp = wc1p[k2 * 32 + l];
                h = fmaf(bcastf(x2, 2 * k2 + 0), bflo(wp), h);
                h = fmaf(bcastf(x2, 2 * k2 + 1), bfhi(wp), h);
            }
            h = fmaxf(h, 0.0f);
            float p0 = (lane < 32) ? h * w2a : 0.0f;
            float p1 = (lane < 32) ? h * w2b : 0.0f;
            #pragma unroll
            for (int off = 1; off < 64; off <<= 1) {
                p0 += __shfl_xor(p0, off, 64);
                p1 += __shfl_xor(p1, off, 64);
            }
            if (lane == 0) {
                out[(size_t)node * 2 + 0] = p0 + bc20;
                out[(size_t)node * 2 + 1] = p1 + bc21;
            }
        }
    }
}

extern "C" void kernel_launch(void* const* d_in, const int* in_sizes, int n_in,
                              void* d_out, int out_size, void* d_ws, size_t ws_size,
                              hipStream_t stream)
{
    const float* feat = (const float*)d_in[0];
    const int*   eidx = (const int*)d_in[1];
    const float* W1   = (const float*)d_in[2];
    const float* b1   = (const float*)d_in[3];
    const float* W2   = (const float*)d_in[4];
    const float* b2   = (const float*)d_in[5];
    const float* Wc1  = (const float*)d_in[6];
    const float* bc1  = (const float*)d_in[7];
    const float* Wc2  = (const float*)d_in[8];
    const float* bc2  = (const float*)d_in[9];

    int n = in_sizes[0] / D;    // 100000
    int E = in_sizes[1] / 2;    // 1600000
    const int* src = eidx;
    const int* dst = eidx + E;

    // workspace layout (words)
    int*   cnt      = (int*)d_ws;               // [n]
    int*   partials = cnt + n;                  // [128]
    int*   blockoff = partials + 128;           // [128]
    int*   rowptr   = blockoff + 128;           // [n+1]
    int*   cursor   = rowptr + n + 1;           // [n]
    int*   adj      = cursor + n;               // [E]
    float* x1       = (float*)(adj + E);        // [n*64]

    int nb = (n + TSCAN - 1) / TSCAN;           // 98

    // CSR build (reused by both layers)
    hipMemsetAsync(cnt, 0, (size_t)n * sizeof(int), stream);
    hist_kernel<<<6250, 256, 0, stream>>>(dst, cnt, E);
    partial_kernel<<<nb, TSCAN, 0, stream>>>(cnt, partials, n);
    scanp_kernel<<<1, 128, 0, stream>>>(partials, blockoff, nb);
    rowptr_kernel<<<nb, TSCAN, 0, stream>>>(cnt, blockoff, rowptr, cursor, n);
    fill_kernel<<<6250, 256, 0, stream>>>(src, dst, cursor, adj, E);

    // 1024 blocks = exactly 4 blocks/CU at 32KB LDS, 8 waves each -> 32 waves/CU.
    // Layer 1: x1 = relu(SAGE(feat)); LDS exactly 32KB
    sage_kernel<false><<<1024, 512, 32768, stream>>>(
        feat, rowptr, adj, W1, b1,
        nullptr, nullptr, nullptr, nullptr, x1, n);

    // Layer 2 + head: d_out = head(relu(SAGE(x1))); LDS 36KB
    sage_kernel<true><<<1024, 512, 32768 + 4096, stream>>>(
        x1, rowptr, adj, W2, b2,
        Wc1, bc1, Wc2, bc2, (float*)d_out, n);
}

// Round 8
// 1614.559 us; speedup vs baseline: 1.0771x; 1.0045x over previous
//
#include <hip/hip_runtime.h>

#define D 64
#define TSCAN 1024

typedef unsigned int   u32;
typedef unsigned short u16;

__device__ __forceinline__ float bcastf(float v, int l) {
    return __uint_as_float(__builtin_amdgcn_readlane(__float_as_uint(v), l));
}
__device__ __forceinline__ u32 f2bf(float f) {
    u32 u = __float_as_uint(f);
    return (u + 0x7fffu + ((u >> 16) & 1u)) >> 16;
}
__device__ __forceinline__ float bflo(u32 v) { return __uint_as_float(v << 16); }
__device__ __forceinline__ float bfhi(u32 v) { return __uint_as_float(v & 0xffff0000u); }

// ---------- repack: fp32 [n][64] -> slice-major bf16 pairs xsb[s][node][4] ----------
__global__ void __launch_bounds__(256) repack_kernel(
    const float* __restrict__ x, u32* __restrict__ xsb, int n)
{
    int t = blockIdx.x * blockDim.x + threadIdx.x;
    int st = gridDim.x * blockDim.x;
    int total = n * 8;
    for (int u = t; u < total; u += st) {
        int node = u >> 3, s = u & 7;
        const float4* p = (const float4*)(x + (size_t)node * 64 + s * 8);
        float4 a = p[0], b = p[1];
        u32* o = xsb + (size_t)s * n * 4 + (size_t)node * 4;
        o[0] = f2bf(a.x) | (f2bf(a.y) << 16);
        o[1] = f2bf(a.z) | (f2bf(a.w) << 16);
        o[2] = f2bf(b.x) | (f2bf(b.y) << 16);
        o[3] = f2bf(b.z) | (f2bf(b.w) << 16);
    }
}

// ---------- CSR build ----------
__global__ void __launch_bounds__(256) hist_kernel(
    const int* __restrict__ dst, int* __restrict__ cnt, int E)
{
    int t = blockIdx.x * blockDim.x + threadIdx.x;
    int st = gridDim.x * blockDim.x;
    for (int e = t; e < E; e += st) atomicAdd(&cnt[dst[e]], 1);
}

__global__ void __launch_bounds__(TSCAN) partial_kernel(
    const int* __restrict__ cnt, int* __restrict__ partials, int n)
{
    __shared__ int red[TSCAN];
    int i = blockIdx.x * TSCAN + threadIdx.x;
    red[threadIdx.x] = (i < n) ? cnt[i] : 0;
    __syncthreads();
    for (int off = TSCAN / 2; off > 0; off >>= 1) {
        if (threadIdx.x < off) red[threadIdx.x] += red[threadIdx.x + off];
        __syncthreads();
    }
    if (threadIdx.x == 0) partials[blockIdx.x] = red[0];
}

__global__ void __launch_bounds__(128) scanp_kernel(
    const int* __restrict__ partials, int* __restrict__ blockoff, int nb)
{
    __shared__ int s[128];
    int t = threadIdx.x;
    int orig = (t < nb) ? partials[t] : 0;
    s[t] = orig;
    __syncthreads();
    for (int off = 1; off < 128; off <<= 1) {
        int v = (t >= off) ? s[t - off] : 0;
        __syncthreads();
        s[t] += v;
        __syncthreads();
    }
    if (t < nb) blockoff[t] = s[t] - orig;   // exclusive
}

__global__ void __launch_bounds__(TSCAN) rowptr_kernel(
    const int* __restrict__ cnt, const int* __restrict__ blockoff,
    int* __restrict__ rowptr, int* __restrict__ cursor, int n)
{
    __shared__ int s[TSCAN];
    int b = blockIdx.x;
    int i = b * TSCAN + threadIdx.x;
    int v = (i < n) ? cnt[i] : 0;
    s[threadIdx.x] = v;
    __syncthreads();
    for (int off = 1; off < TSCAN; off <<= 1) {
        int x = (threadIdx.x >= off) ? s[threadIdx.x - off] : 0;
        __syncthreads();
        s[threadIdx.x] += x;
        __syncthreads();
    }
    if (i < n) {
        int excl = blockoff[b] + s[threadIdx.x] - v;
        rowptr[i] = excl;
        cursor[i] = excl;
        if (i == n - 1) rowptr[n] = excl + v;
    }
}

__global__ void __launch_bounds__(256) fill_kernel(
    const int* __restrict__ src, const int* __restrict__ dst,
    int* __restrict__ cursor, int* __restrict__ adj, int E)
{
    int t = blockIdx.x * blockDim.x + threadIdx.x;
    int st = gridDim.x * blockDim.x;
    for (int e = t; e < E; e += st) {
        int p = atomicAdd(&cursor[dst[e]], 1);
        adj[p] = src[e];
    }
}

// ---------- aggregation: slice-per-XCD gather-mean ----------
// blockIdx%8 = feature slice (maps to XCD via round-robin dispatch), so each
// XCD gathers from its own 1.6MB bf16 slice table -> L2-resident.
// Wave per node: lane = 4*edge_slot + pair; 16 edges per load instruction.
__global__ void __launch_bounds__(512) agg_kernel(
    const u32*   __restrict__ xsb,     // [8][n][4] bf16 pairs, slice-major
    const int*   __restrict__ rowptr,  // [n+1]
    const int*   __restrict__ adj,     // [E]
    float*       __restrict__ agg,     // [n][64] fp32 means
    int n, int nchunk)
{
    int s  = blockIdx.x & 7;
    int cb = blockIdx.x >> 3;
    const u32* xs = xsb + (size_t)s * n * 4;
    int c0 = cb * nchunk;
    int c1 = min(n, c0 + nchunk);
    int w    = threadIdx.x >> 6;
    int lane = threadIdx.x & 63;
    int es   = lane >> 2;     // edge slot 0..15
    int pr   = lane & 3;      // pair index 0..3

    for (int node = c0 + w; node < c1; node += 8) {
        int ro = rowptr[node], re = rowptr[node + 1];
        float ax = 0.f, ay = 0.f;
        for (int i = ro; i < re; i += 16) {
            int p = i + es;
            bool bv = p < re;
            int a = bv ? adj[p] : 0;
            u32 v = xs[(size_t)a * 4 + pr];
            if (bv) { ax += bflo(v); ay += bfhi(v); }
        }
        // reduce across edge slots (lane bits 2..5)
        ax += __shfl_xor(ax, 4, 64);  ay += __shfl_xor(ay, 4, 64);
        ax += __shfl_xor(ax, 8, 64);  ay += __shfl_xor(ay, 8, 64);
        ax += __shfl_xor(ax, 16, 64); ay += __shfl_xor(ay, 16, 64);
        ax += __shfl_xor(ax, 32, 64); ay += __shfl_xor(ay, 32, 64);
        if (lane < 4) {
            float inv = 1.0f / fmaxf((float)(re - ro), 1.0f);
            float2 o = make_float2(ax * inv, ay * inv);
            *(float2*)(agg + (size_t)node * 64 + s * 8 + 2 * pr) = o;
        }
    }
}

// ---------- concat-linear (+ optional head), pure streaming ----------
// Wave per node; lane j owns output channel j. Self features from slice-major
// bf16 table, neighbor means from fp32 agg (both sequential reads).
template <bool HEAD>
__global__ void __launch_bounds__(512, 8) mlp_kernel(
    const u32*   __restrict__ xsb,     // [8][n][4] self features (bf16 pairs)
    const float* __restrict__ agg,     // [n][64] neighbor means
    const float* __restrict__ W,       // [64, 128] row-major
    const float* __restrict__ b,       // [64]
    const float* __restrict__ Wc1,     // [32, 64]  (HEAD only)
    const float* __restrict__ bc1,     // [32]
    const float* __restrict__ Wc2,     // [2, 32]
    const float* __restrict__ bc2,     // [2]
    void*        __restrict__ out_,    // HEAD ? float[n,2] : u32 slice-major
    int n)
{
    extern __shared__ float smem[];
    float4* Wt4 = (float4*)smem;               // 8192 floats = 32KB
    float*  Wt  = smem;
    u32*    wc1p = (u32*)(smem + 8192);        // 1024 u32 = 4KB (HEAD)

    for (int d = threadIdx.x; d < 64 * 128; d += blockDim.x) {
        int k4 = d >> 8;
        int j  = (d >> 2) & 63;
        int kk = d & 3;
        Wt[d] = W[j * 128 + k4 * 4 + kk];
    }
    if (HEAD) {
        for (int d = threadIdx.x; d < 32 * 32; d += blockDim.x) {
            int k2 = d >> 5, l = d & 31;
            wc1p[d] = f2bf(Wc1[l * 64 + 2 * k2]) | (f2bf(Wc1[l * 64 + 2 * k2 + 1]) << 16);
        }
    }
    __syncthreads();

    int lane = threadIdx.x & 63;
    int l    = lane & 31;
    float bj = b[lane];
    float bc1r = 0.f, w2a = 0.f, w2b = 0.f, bc20 = 0.f, bc21 = 0.f;
    if (HEAD) {
        bc1r = bc1[l];
        w2a  = Wc2[l];
        w2b  = Wc2[32 + l];
        bc20 = bc2[0];
        bc21 = bc2[1];
    }

    size_t n4 = (size_t)n * 4;
    int sl = lane >> 3;              // slice of feature `lane`
    int pw = (lane & 7) >> 1;        // pair word within slice
    int wid = (blockIdx.x * blockDim.x + threadIdx.x) >> 6;
    int nw  = (gridDim.x * blockDim.x) >> 6;
    for (int node = wid; node < n; node += nw) {
        u32 wv = xsb[(size_t)sl * n4 + (size_t)node * 4 + pw];
        float xv = (lane & 1) ? bfhi(wv) : bflo(wv);
        float av = agg[(size_t)node * 64 + lane];

        float sum = bj;
        #pragma unroll
        for (int k4 = 0; k4 < 16; ++k4) {
            float4 w = Wt4[k4 * 64 + lane];
            sum = fmaf(bcastf(xv, 4 * k4 + 0), w.x, sum);
            sum = fmaf(bcastf(xv, 4 * k4 + 1), w.y, sum);
            sum = fmaf(bcastf(xv, 4 * k4 + 2), w.z, sum);
            sum = fmaf(bcastf(xv, 4 * k4 + 3), w.w, sum);
        }
        #pragma unroll
        for (int k4 = 16; k4 < 32; ++k4) {
            float4 w = Wt4[k4 * 64 + lane];
            int kk = 4 * (k4 - 16);
            sum = fmaf(bcastf(av, kk + 0), w.x, sum);
            sum = fmaf(bcastf(av, kk + 1), w.y, sum);
            sum = fmaf(bcastf(av, kk + 2), w.z, sum);
            sum = fmaf(bcastf(av, kk + 3), w.w, sum);
        }
        float x2 = fmaxf(sum, 0.0f);   // ReLU; lane j holds channel j

        if (!HEAD) {
            // pack pairs, write slice-major bf16 (even lanes store dwords)
            u32 bits = f2bf(x2);
            u32 part = (u32)__shfl_xor((int)bits, 1, 64);
            if (!(lane & 1))
                ((u32*)out_)[(size_t)sl * n4 + (size_t)node * 4 + pw] = bits | (part << 16);
        } else {
            float h = bc1r;
            #pragma unroll
            for (int k2 = 0; k2 < 32; ++k2) {
                u32 wp = wc1p[k2 * 32 + l];
                h = fmaf(bcastf(x2, 2 * k2 + 0), bflo(wp), h);
                h = fmaf(bcastf(x2, 2 * k2 + 1), bfhi(wp), h);
            }
            h = fmaxf(h, 0.0f);
            float p0 = (lane < 32) ? h * w2a : 0.0f;
            float p1 = (lane < 32) ? h * w2b : 0.0f;
            #pragma unroll
            for (int off = 1; off < 64; off <<= 1) {
                p0 += __shfl_xor(p0, off, 64);
                p1 += __shfl_xor(p1, off, 64);
            }
            if (lane == 0) {
                float* outf = (float*)out_;
                outf[(size_t)node * 2 + 0] = p0 + bc20;
                outf[(size_t)node * 2 + 1] = p1 + bc21;
            }
        }
    }
}

extern "C" void kernel_launch(void* const* d_in, const int* in_sizes, int n_in,
                              void* d_out, int out_size, void* d_ws, size_t ws_size,
                              hipStream_t stream)
{
    const float* feat = (const float*)d_in[0];
    const int*   eidx = (const int*)d_in[1];
    const float* W1   = (const float*)d_in[2];
    const float* b1   = (const float*)d_in[3];
    const float* W2   = (const float*)d_in[4];
    const float* b2   = (const float*)d_in[5];
    const float* Wc1  = (const float*)d_in[6];
    const float* bc1  = (const float*)d_in[7];
    const float* Wc2  = (const float*)d_in[8];
    const float* bc2  = (const float*)d_in[9];

    int n = in_sizes[0] / D;    // 100000
    int E = in_sizes[1] / 2;    // 1600000
    const int* src = eidx;
    const int* dst = eidx + E;

    // workspace layout (words) ~59MB total
    int*   cnt      = (int*)d_ws;               // [n]
    int*   partials = cnt + n;                  // [128]
    int*   blockoff = partials + 128;           // [128]
    int*   rowptr   = blockoff + 128;           // [n+1]
    int*   cursor   = rowptr + n + 1;           // [n]
    int*   adj      = cursor + n;               // [E]
    u32*   xsb      = (u32*)(adj + E);          // [8][n][4] bf16 pairs
    u32*   x1sb     = xsb + (size_t)n * 32;     // [8][n][4]
    float* agg      = (float*)(x1sb + (size_t)n * 32);  // [n][64] fp32

    int nb = (n + TSCAN - 1) / TSCAN;           // 98

    // feature repack + CSR build
    repack_kernel<<<1024, 256, 0, stream>>>(feat, xsb, n);
    hipMemsetAsync(cnt, 0, (size_t)n * sizeof(int), stream);
    hist_kernel<<<6250, 256, 0, stream>>>(dst, cnt, E);
    partial_kernel<<<nb, TSCAN, 0, stream>>>(cnt, partials, n);
    scanp_kernel<<<1, 128, 0, stream>>>(partials, blockoff, nb);
    rowptr_kernel<<<nb, TSCAN, 0, stream>>>(cnt, blockoff, rowptr, cursor, n);
    fill_kernel<<<6250, 256, 0, stream>>>(src, dst, cursor, adj, E);

    int nchunk = (n + 511) / 512;   // nodes per chunk (512 chunks x 8 slices)

    // Layer 1
    agg_kernel<<<4096, 512, 0, stream>>>(xsb, rowptr, adj, agg, n, nchunk);
    mlp_kernel<false><<<1024, 512, 32768, stream>>>(
        xsb, agg, W1, b1, nullptr, nullptr, nullptr, nullptr, (void*)x1sb, n);

    // Layer 2 + head
    agg_kernel<<<4096, 512, 0, stream>>>(x1sb, rowptr, adj, agg, n, nchunk);
    mlp_kernel<true><<<1024, 512, 32768 + 4096, stream>>>(
        x1sb, agg, W2, b2, Wc1, bc1, Wc2, bc2, d_out, n);
}

// Round 9
// 1472.850 us; speedup vs baseline: 1.1808x; 1.0962x over previous
//
#include <hip/hip_runtime.h>

#define D 64
#define TSCAN 1024

typedef unsigned int   u32;
typedef unsigned short u16;

__device__ __forceinline__ float bcastf(float v, int l) {
    return __uint_as_float(__builtin_amdgcn_readlane(__float_as_uint(v), l));
}
__device__ __forceinline__ u32 f2bf(float f) {
    u32 u = __float_as_uint(f);
    return (u + 0x7fffu + ((u >> 16) & 1u)) >> 16;
}
__device__ __forceinline__ float bflo(u32 v) { return __uint_as_float(v << 16); }
__device__ __forceinline__ float bfhi(u32 v) { return __uint_as_float(v & 0xffff0000u); }

// ---------- repack: fp32 [n][64] -> slice-major bf16 pairs xsb[s][node][4] ----------
__global__ void __launch_bounds__(256) repack_kernel(
    const float* __restrict__ x, u32* __restrict__ xsb, int n)
{
    int t = blockIdx.x * blockDim.x + threadIdx.x;
    int st = gridDim.x * blockDim.x;
    int total = n * 8;
    for (int u = t; u < total; u += st) {
        int node = u >> 3, s = u & 7;
        const float4* p = (const float4*)(x + (size_t)node * 64 + s * 8);
        float4 a = p[0], b = p[1];
        u32* o = xsb + (size_t)s * n * 4 + (size_t)node * 4;
        o[0] = f2bf(a.x) | (f2bf(a.y) << 16);
        o[1] = f2bf(a.z) | (f2bf(a.w) << 16);
        o[2] = f2bf(b.x) | (f2bf(b.y) << 16);
        o[3] = f2bf(b.z) | (f2bf(b.w) << 16);
    }
}

// ---------- CSR build ----------
__global__ void __launch_bounds__(256) hist_kernel(
    const int* __restrict__ dst, int* __restrict__ cnt, int E)
{
    int t = blockIdx.x * blockDim.x + threadIdx.x;
    int st = gridDim.x * blockDim.x;
    for (int e = t; e < E; e += st) atomicAdd(&cnt[dst[e]], 1);
}

__global__ void __launch_bounds__(TSCAN) partial_kernel(
    const int* __restrict__ cnt, int* __restrict__ partials, int n)
{
    __shared__ int red[TSCAN];
    int i = blockIdx.x * TSCAN + threadIdx.x;
    red[threadIdx.x] = (i < n) ? cnt[i] : 0;
    __syncthreads();
    for (int off = TSCAN / 2; off > 0; off >>= 1) {
        if (threadIdx.x < off) red[threadIdx.x] += red[threadIdx.x + off];
        __syncthreads();
    }
    if (threadIdx.x == 0) partials[blockIdx.x] = red[0];
}

__global__ void __launch_bounds__(128) scanp_kernel(
    const int* __restrict__ partials, int* __restrict__ blockoff, int nb)
{
    __shared__ int s[128];
    int t = threadIdx.x;
    int orig = (t < nb) ? partials[t] : 0;
    s[t] = orig;
    __syncthreads();
    for (int off = 1; off < 128; off <<= 1) {
        int v = (t >= off) ? s[t - off] : 0;
        __syncthreads();
        s[t] += v;
        __syncthreads();
    }
    if (t < nb) blockoff[t] = s[t] - orig;   // exclusive
}

__global__ void __launch_bounds__(TSCAN) rowptr_kernel(
    const int* __restrict__ cnt, const int* __restrict__ blockoff,
    int* __restrict__ rowptr, int* __restrict__ cursor, int n)
{
    __shared__ int s[TSCAN];
    int b = blockIdx.x;
    int i = b * TSCAN + threadIdx.x;
    int v = (i < n) ? cnt[i] : 0;
    s[threadIdx.x] = v;
    __syncthreads();
    for (int off = 1; off < TSCAN; off <<= 1) {
        int x = (threadIdx.x >= off) ? s[threadIdx.x - off] : 0;
        __syncthreads();
        s[threadIdx.x] += x;
        __syncthreads();
    }
    if (i < n) {
        int excl = blockoff[b] + s[threadIdx.x] - v;
        rowptr[i] = excl;
        cursor[i] = excl;
        if (i == n - 1) rowptr[n] = excl + v;
    }
}

__global__ void __launch_bounds__(256) fill_kernel(
    const int* __restrict__ src, const int* __restrict__ dst,
    int* __restrict__ cursor, int* __restrict__ adj, int E)
{
    int t = blockIdx.x * blockDim.x + threadIdx.x;
    int st = gridDim.x * blockDim.x;
    for (int e = t; e < E; e += st) {
        int p = atomicAdd(&cursor[dst[e]], 1);
        adj[p] = src[e];
    }
}

// ---------- aggregation: slice-per-XCD gather-mean ----------
// blockIdx%8 = feature slice -> XCD round-robin; each XCD gathers from its own
// 1.6MB bf16 slice table (L2-resident). Wave per node: lane = 4*edge+pair.
// Output agg2[s][node][8]: slice-contiguous so partial-line writes share lines
// only with same-XCD neighbors.
__global__ void __launch_bounds__(512) agg_kernel(
    const u32*   __restrict__ xsb,     // [8][n][4] bf16 pairs, slice-major
    const int*   __restrict__ rowptr,  // [n+1]
    const int*   __restrict__ adj,     // [E]
    float*       __restrict__ agg2,    // [8][n][8] fp32 means, slice-major
    int n, int nchunk)
{
    int s  = blockIdx.x & 7;
    int cb = blockIdx.x >> 3;
    const u32* xs = xsb + (size_t)s * n * 4;
    int c0 = cb * nchunk;
    int c1 = min(n, c0 + nchunk);
    int w    = threadIdx.x >> 6;
    int lane = threadIdx.x & 63;
    int es   = lane >> 2;     // edge slot 0..15
    int pr   = lane & 3;      // pair index 0..3

    for (int node = c0 + w; node < c1; node += 8) {
        int ro = rowptr[node], re = rowptr[node + 1];
        float ax = 0.f, ay = 0.f;
        for (int i = ro; i < re; i += 16) {
            int p = i + es;
            bool bv = p < re;
            int a = bv ? adj[p] : 0;
            u32 v = xs[(size_t)a * 4 + pr];
            if (bv) { ax += bflo(v); ay += bfhi(v); }
        }
        ax += __shfl_xor(ax, 4, 64);  ay += __shfl_xor(ay, 4, 64);
        ax += __shfl_xor(ax, 8, 64);  ay += __shfl_xor(ay, 8, 64);
        ax += __shfl_xor(ax, 16, 64); ay += __shfl_xor(ay, 16, 64);
        ax += __shfl_xor(ax, 32, 64); ay += __shfl_xor(ay, 32, 64);
        if (lane < 4) {
            float inv = 1.0f / fmaxf((float)(re - ro), 1.0f);
            float2 o = make_float2(ax * inv, ay * inv);
            *(float2*)(agg2 + ((size_t)s * n + node) * 8 + 2 * pr) = o;
        }
    }
}

// ---------- concat-linear (+ optional head), 4 nodes per wave ----------
// Lane j owns output channel j for all 4 nodes. All global accesses line-pure:
// self (fp32 rows or 64B-per-slice bf16 groups), agg2 (128B per slice), writes
// adjacent across the 4-node unroll. One LDS weight read feeds 4 nodes.
template <bool HEAD>
__global__ void __launch_bounds__(512, 8) mlp_kernel(
    const float* __restrict__ xf,      // [n][64] fp32 self (HEAD=false)
    const u32*   __restrict__ xb,      // [8][n][4] bf16 self (HEAD=true)
    const float* __restrict__ agg2,    // [8][n][8]
    const float* __restrict__ W,       // [64, 128] row-major
    const float* __restrict__ b,       // [64]
    const float* __restrict__ Wc1,     // [32, 64]  (HEAD only)
    const float* __restrict__ bc1,     // [32]
    const float* __restrict__ Wc2,     // [2, 32]
    const float* __restrict__ bc2,     // [2]
    float*       __restrict__ outf,    // HEAD: [n][2]
    u32*         __restrict__ outsb,   // !HEAD: [8][n][4]
    int n)
{
    extern __shared__ float smem[];
    float4* Wt4 = (float4*)smem;               // 8192 floats = 32KB
    float*  Wt  = smem;
    u32*    wc1p = (u32*)(smem + 8192);        // 1024 u32 = 4KB (HEAD)

    for (int d = threadIdx.x; d < 64 * 128; d += blockDim.x) {
        int k4 = d >> 8;
        int j  = (d >> 2) & 63;
        int kk = d & 3;
        Wt[d] = W[j * 128 + k4 * 4 + kk];
    }
    if (HEAD) {
        for (int d = threadIdx.x; d < 32 * 32; d += blockDim.x) {
            int k2 = d >> 5, l = d & 31;
            wc1p[d] = f2bf(Wc1[l * 64 + 2 * k2]) | (f2bf(Wc1[l * 64 + 2 * k2 + 1]) << 16);
        }
    }
    __syncthreads();

    int lane = threadIdx.x & 63;
    int sl   = lane >> 3;        // slice of channel `lane`
    int w8   = lane & 7;         // word within slice (fp32 agg2)
    int l    = lane & 31;
    float bj = b[lane];
    float bc1r = 0.f, w2a = 0.f, w2b = 0.f, bc20 = 0.f, bc21 = 0.f;
    if (HEAD) {
        bc1r = bc1[l];
        w2a  = Wc2[l];
        w2b  = Wc2[32 + l];
        bc20 = bc2[0];
        bc21 = bc2[1];
    }

    size_t n4 = (size_t)n * 4;
    int ngr = (n + 3) >> 2;
    int wid = (blockIdx.x * blockDim.x + threadIdx.x) >> 6;
    int nw  = (gridDim.x * blockDim.x) >> 6;
    for (int g = wid; g < ngr; g += nw) {
        int nb = g * 4;
        int i0 = nb, i1 = min(nb + 1, n - 1), i2 = min(nb + 2, n - 1), i3 = min(nb + 3, n - 1);

        // self features (channel `lane`) for 4 nodes
        float xv0, xv1, xv2, xv3;
        if (!HEAD) {
            xv0 = xf[(size_t)i0 * 64 + lane];
            xv1 = xf[(size_t)i1 * 64 + lane];
            xv2 = xf[(size_t)i2 * 64 + lane];
            xv3 = xf[(size_t)i3 * 64 + lane];
        } else {
            int pw = (lane & 7) >> 1;
            const u32* xs = xb + (size_t)sl * n4;
            u32 w0 = xs[(size_t)i0 * 4 + pw];
            u32 w1 = xs[(size_t)i1 * 4 + pw];
            u32 w2 = xs[(size_t)i2 * 4 + pw];
            u32 w3 = xs[(size_t)i3 * 4 + pw];
            xv0 = (lane & 1) ? bfhi(w0) : bflo(w0);
            xv1 = (lane & 1) ? bfhi(w1) : bflo(w1);
            xv2 = (lane & 1) ? bfhi(w2) : bflo(w2);
            xv3 = (lane & 1) ? bfhi(w3) : bflo(w3);
        }
        // neighbor means (channel `lane`) for 4 nodes
        const float* ag = agg2 + ((size_t)sl * n) * 8 + w8;
        float av0 = ag[(size_t)i0 * 8];
        float av1 = ag[(size_t)i1 * 8];
        float av2 = ag[(size_t)i2 * 8];
        float av3 = ag[(size_t)i3 * 8];

        float s0 = bj, s1 = bj, s2 = bj, s3 = bj;
        #pragma unroll
        for (int k4 = 0; k4 < 16; ++k4) {   // self half
            float4 w = Wt4[k4 * 64 + lane];
            s0 = fmaf(bcastf(xv0, 4*k4+0), w.x, s0); s0 = fmaf(bcastf(xv0, 4*k4+1), w.y, s0);
            s0 = fmaf(bcastf(xv0, 4*k4+2), w.z, s0); s0 = fmaf(bcastf(xv0, 4*k4+3), w.w, s0);
            s1 = fmaf(bcastf(xv1, 4*k4+0), w.x, s1); s1 = fmaf(bcastf(xv1, 4*k4+1), w.y, s1);
            s1 = fmaf(bcastf(xv1, 4*k4+2), w.z, s1); s1 = fmaf(bcastf(xv1, 4*k4+3), w.w, s1);
            s2 = fmaf(bcastf(xv2, 4*k4+0), w.x, s2); s2 = fmaf(bcastf(xv2, 4*k4+1), w.y, s2);
            s2 = fmaf(bcastf(xv2, 4*k4+2), w.z, s2); s2 = fmaf(bcastf(xv2, 4*k4+3), w.w, s2);
            s3 = fmaf(bcastf(xv3, 4*k4+0), w.x, s3); s3 = fmaf(bcastf(xv3, 4*k4+1), w.y, s3);
            s3 = fmaf(bcastf(xv3, 4*k4+2), w.z, s3); s3 = fmaf(bcastf(xv3, 4*k4+3), w.w, s3);
        }
        #pragma unroll
        for (int k4 = 16; k4 < 32; ++k4) {  // neighbor half
            float4 w = Wt4[k4 * 64 + lane];
            int kk = 4 * (k4 - 16);
            s0 = fmaf(bcastf(av0, kk+0), w.x, s0); s0 = fmaf(bcastf(av0, kk+1), w.y, s0);
            s0 = fmaf(bcastf(av0, kk+2), w.z, s0); s0 = fmaf(bcastf(av0, kk+3), w.w, s0);
            s1 = fmaf(bcastf(av1, kk+0), w.x, s1); s1 = fmaf(bcastf(av1, kk+1), w.y, s1);
            s1 = fmaf(bcastf(av1, kk+2), w.z, s1); s1 = fmaf(bcastf(av1, kk+3), w.w, s1);
            s2 = fmaf(bcastf(av2, kk+0), w.x, s2); s2 = fmaf(bcastf(av2, kk+1), w.y, s2);
            s2 = fmaf(bcastf(av2, kk+2), w.z, s2); s2 = fmaf(bcastf(av2, kk+3), w.w, s2);
            s3 = fmaf(bcastf(av3, kk+0), w.x, s3); s3 = fmaf(bcastf(av3, kk+1), w.y, s3);
            s3 = fmaf(bcastf(av3, kk+2), w.z, s3); s3 = fmaf(bcastf(av3, kk+3), w.w, s3);
        }
        float x20 = fmaxf(s0, 0.f), x21 = fmaxf(s1, 0.f);
        float x22 = fmaxf(s2, 0.f), x23 = fmaxf(s3, 0.f);

        if (!HEAD) {
            int pw = (lane & 7) >> 1;
            u32* os = outsb + (size_t)sl * n4 + pw;
            u32 b0 = f2bf(x20), p0 = (u32)__shfl_xor((int)b0, 1, 64);
            u32 b1 = f2bf(x21), p1 = (u32)__shfl_xor((int)b1, 1, 64);
            u32 b2 = f2bf(x22), p2 = (u32)__shfl_xor((int)b2, 1, 64);
            u32 b3 = f2bf(x23), p3 = (u32)__shfl_xor((int)b3, 1, 64);
            if (!(lane & 1)) {
                os[(size_t)i0 * 4] = b0 | (p0 << 16);
                if (nb + 1 < n) os[(size_t)i1 * 4] = b1 | (p1 << 16);
                if (nb + 2 < n) os[(size_t)i2 * 4] = b2 | (p2 << 16);
                if (nb + 3 < n) os[(size_t)i3 * 4] = b3 | (p3 << 16);
            }
        } else {
            #pragma unroll
            for (int a = 0; a < 4; ++a) {
                float x2 = (a == 0) ? x20 : (a == 1) ? x21 : (a == 2) ? x22 : x23;
                float h = bc1r;
                #pragma unroll
                for (int k2 = 0; k2 < 32; ++k2) {
                    u32 wp = wc1p[k2 * 32 + l];
                    h = fmaf(bcastf(x2, 2*k2+0), bflo(wp), h);
                    h = fmaf(bcastf(x2, 2*k2+1), bfhi(wp), h);
                }
                h = fmaxf(h, 0.f);
                float p0 = (lane < 32) ? h * w2a : 0.f;
                float p1 = (lane < 32) ? h * w2b : 0.f;
                #pragma unroll
                for (int off = 1; off < 64; off <<= 1) {
                    p0 += __shfl_xor(p0, off, 64);
                    p1 += __shfl_xor(p1, off, 64);
                }
                if (lane == 0 && nb + a < n) {
                    float2 o = make_float2(p0 + bc20, p1 + bc21);
                    *(float2*)(outf + (size_t)(nb + a) * 2) = o;
                }
            }
        }
    }
}

extern "C" void kernel_launch(void* const* d_in, const int* in_sizes, int n_in,
                              void* d_out, int out_size, void* d_ws, size_t ws_size,
                              hipStream_t stream)
{
    const float* feat = (const float*)d_in[0];
    const int*   eidx = (const int*)d_in[1];
    const float* W1   = (const float*)d_in[2];
    const float* b1   = (const float*)d_in[3];
    const float* W2   = (const float*)d_in[4];
    const float* b2   = (const float*)d_in[5];
    const float* Wc1  = (const float*)d_in[6];
    const float* bc1  = (const float*)d_in[7];
    const float* Wc2  = (const float*)d_in[8];
    const float* bc2  = (const float*)d_in[9];

    int n = in_sizes[0] / D;    // 100000
    int E = in_sizes[1] / 2;    // 1600000
    const int* src = eidx;
    const int* dst = eidx + E;

    // workspace layout (words) ~59MB
    int*   cnt      = (int*)d_ws;                       // [n]
    int*   partials = cnt + n;                          // [128]
    int*   blockoff = partials + 128;                   // [128]
    int*   rowptr   = blockoff + 128;                   // [n+1]
    int*   cursor   = rowptr + n + 1;                   // [n]
    int*   adj      = cursor + n;                       // [E]
    u32*   xsb      = (u32*)(adj + E);                  // [8][n][4]
    u32*   x1sb     = xsb + (size_t)n * 32;             // [8][n][4]
    float* agg2     = (float*)(x1sb + (size_t)n * 32);  // [8][n][8]

    int nb = (n + TSCAN - 1) / TSCAN;                   // 98

    // feature repack + CSR build
    repack_kernel<<<1024, 256, 0, stream>>>(feat, xsb, n);
    hipMemsetAsync(cnt, 0, (size_t)n * sizeof(int), stream);
    hist_kernel<<<6250, 256, 0, stream>>>(dst, cnt, E);
    partial_kernel<<<nb, TSCAN, 0, stream>>>(cnt, partials, n);
    scanp_kernel<<<1, 128, 0, stream>>>(partials, blockoff, nb);
    rowptr_kernel<<<nb, TSCAN, 0, stream>>>(cnt, blockoff, rowptr, cursor, n);
    fill_kernel<<<6250, 256, 0, stream>>>(src, dst, cursor, adj, E);

    int nchunk = (n + 511) / 512;   // 512 chunks x 8 slices

    // Layer 1: agg from xsb; mlp self from fp32 feat -> x1sb
    agg_kernel<<<4096, 512, 0, stream>>>(xsb, rowptr, adj, agg2, n, nchunk);
    mlp_kernel<false><<<512, 512, 32768, stream>>>(
        feat, nullptr, agg2, W1, b1,
        nullptr, nullptr, nullptr, nullptr, nullptr, x1sb, n);

    // Layer 2 + head: agg from x1sb; mlp self from x1sb -> logits
    agg_kernel<<<4096, 512, 0, stream>>>(x1sb, rowptr, adj, agg2, n, nchunk);
    mlp_kernel<true><<<512, 512, 32768 + 4096, stream>>>(
        nullptr, x1sb, agg2, W2, b2,
        Wc1, bc1, Wc2, bc2, (float*)d_out, nullptr, n);
}

// Round 10
// 1459.363 us; speedup vs baseline: 1.1917x; 1.0092x over previous
//
#include <hip/hip_runtime.h>

#define D 64
#define TSCAN 1024

typedef unsigned int   u32;
typedef unsigned short u16;

__device__ __forceinline__ float bcastf(float v, int l) {
    return __uint_as_float(__builtin_amdgcn_readlane(__float_as_uint(v), l));
}
__device__ __forceinline__ u32 f2bf(float f) {
    u32 u = __float_as_uint(f);
    return (u + 0x7fffu + ((u >> 16) & 1u)) >> 16;
}
__device__ __forceinline__ float bflo(u32 v) { return __uint_as_float(v << 16); }
__device__ __forceinline__ float bfhi(u32 v) { return __uint_as_float(v & 0xffff0000u); }

// ---------- fp32 [n][64] -> packed bf16 pairs [n][32] ----------
__global__ void __launch_bounds__(256) tobf16_kernel(
    const float* __restrict__ x, u32* __restrict__ xp, int npairs)
{
    int t = blockIdx.x * blockDim.x + threadIdx.x;
    int st = gridDim.x * blockDim.x;
    for (int i = t; i < npairs; i += st) {
        float2 v = ((const float2*)x)[i];
        xp[i] = f2bf(v.x) | (f2bf(v.y) << 16);
    }
}

// ---------- CSR build ----------
__global__ void __launch_bounds__(256) hist_kernel(
    const int* __restrict__ dst, int* __restrict__ cnt, int E)
{
    int t = blockIdx.x * blockDim.x + threadIdx.x;
    int st = gridDim.x * blockDim.x;
    for (int e = t; e < E; e += st) atomicAdd(&cnt[dst[e]], 1);
}

__global__ void __launch_bounds__(TSCAN) partial_kernel(
    const int* __restrict__ cnt, int* __restrict__ partials, int n)
{
    __shared__ int red[TSCAN];
    int i = blockIdx.x * TSCAN + threadIdx.x;
    red[threadIdx.x] = (i < n) ? cnt[i] : 0;
    __syncthreads();
    for (int off = TSCAN / 2; off > 0; off >>= 1) {
        if (threadIdx.x < off) red[threadIdx.x] += red[threadIdx.x + off];
        __syncthreads();
    }
    if (threadIdx.x == 0) partials[blockIdx.x] = red[0];
}

__global__ void __launch_bounds__(128) scanp_kernel(
    const int* __restrict__ partials, int* __restrict__ blockoff, int nb)
{
    __shared__ int s[128];
    int t = threadIdx.x;
    int orig = (t < nb) ? partials[t] : 0;
    s[t] = orig;
    __syncthreads();
    for (int off = 1; off < 128; off <<= 1) {
        int v = (t >= off) ? s[t - off] : 0;
        __syncthreads();
        s[t] += v;
        __syncthreads();
    }
    if (t < nb) blockoff[t] = s[t] - orig;   // exclusive
}

__global__ void __launch_bounds__(TSCAN) rowptr_kernel(
    const int* __restrict__ cnt, const int* __restrict__ blockoff,
    int* __restrict__ rowptr, int* __restrict__ cursor, int n)
{
    __shared__ int s[TSCAN];
    int b = blockIdx.x;
    int i = b * TSCAN + threadIdx.x;
    int v = (i < n) ? cnt[i] : 0;
    s[threadIdx.x] = v;
    __syncthreads();
    for (int off = 1; off < TSCAN; off <<= 1) {
        int x = (threadIdx.x >= off) ? s[threadIdx.x - off] : 0;
        __syncthreads();
        s[threadIdx.x] += x;
        __syncthreads();
    }
    if (i < n) {
        int excl = blockoff[b] + s[threadIdx.x] - v;
        rowptr[i] = excl;
        cursor[i] = excl;
        if (i == n - 1) rowptr[n] = excl + v;
    }
}

__global__ void __launch_bounds__(256) fill_kernel(
    const int* __restrict__ src, const int* __restrict__ dst,
    int* __restrict__ cursor, int* __restrict__ adj, int E)
{
    int t = blockIdx.x * blockDim.x + threadIdx.x;
    int st = gridDim.x * blockDim.x;
    for (int e = t; e < E; e += st) {
        int p = atomicAdd(&cursor[dst[e]], 1);
        adj[p] = src[e];
    }
}

// ---------- fused SAGE layer: R3 schedule, bf16-packed table ----------
// Wave per node. Gather: lanes 0-31 read edge e0's row (32 u32 = 128B), lanes
// 32-63 read edge e1's row. Addresses from wave-uniform scalar adj loads via
// one cndmask -- no shfl, no duplicate halves. One shfl_xor(32) reduce at end.
// Lane m holds feature pair {2m, 2m+1}. MLP: lane j owns output channel j.
template <bool HEAD>
__global__ void __launch_bounds__(512, 8) sage_kernel(
    const u32*   __restrict__ xp,      // [n][32] packed bf16 pairs
    const int*   __restrict__ rowptr,  // [n+1]
    const int*   __restrict__ adj,     // [E]
    const float* __restrict__ W,       // [64, 128] row-major
    const float* __restrict__ b,       // [64]
    const float* __restrict__ Wc1,     // [32, 64]  (HEAD only)
    const float* __restrict__ bc1,     // [32]
    const float* __restrict__ Wc2,     // [2, 32]
    const float* __restrict__ bc2,     // [2]
    void*        __restrict__ out_,    // HEAD ? float[n,2] : u32[n,32]
    int n)
{
    extern __shared__ float smem[];
    float4* Wt4 = (float4*)smem;               // 8192 floats = 32KB: Wt4[k4*64+j]=W[j][4k4..]
    float*  Wt  = smem;
    u32*    wc1p = (u32*)(smem + 8192);        // 1024 u32 = 4KB (HEAD)

    for (int d = threadIdx.x; d < 64 * 128; d += blockDim.x) {
        int k4 = d >> 8;
        int j  = (d >> 2) & 63;
        int kk = d & 3;
        Wt[d] = W[j * 128 + k4 * 4 + kk];
    }
    if (HEAD) {
        for (int d = threadIdx.x; d < 32 * 32; d += blockDim.x) {
            int k2 = d >> 5, l = d & 31;
            wc1p[d] = f2bf(Wc1[l * 64 + 2 * k2]) | (f2bf(Wc1[l * 64 + 2 * k2 + 1]) << 16);
        }
    }
    __syncthreads();

    int lane = threadIdx.x & 63;
    int g    = lane >> 5;          // which edge of the pair this half reads
    int m    = lane & 31;          // feature-pair index
    int l    = lane & 31;
    float bj = b[lane];
    float bc1r = 0.f, w2a = 0.f, w2b = 0.f, bc20 = 0.f, bc21 = 0.f;
    if (HEAD) {
        bc1r = bc1[l];
        w2a  = Wc2[l];
        w2b  = Wc2[32 + l];
        bc20 = bc2[0];
        bc21 = bc2[1];
    }

    int wid  = (blockIdx.x * blockDim.x + threadIdx.x) >> 6;
    int nw   = (gridDim.x * blockDim.x) >> 6;
    for (int node = wid; node < n; node += nw) {
        int ro = rowptr[node], re = rowptr[node + 1];
        int deg = re - ro;
        u32 sv = xp[(size_t)node * 32 + m];       // self row (streaming)
        float xvx = bflo(sv), xvy = bfhi(sv);

        // gather: 4 pair-loads (8 edges) in flight, no shfl in address path
        float ax0 = 0.f, ay0 = 0.f, ax1 = 0.f, ay1 = 0.f;
        int i = ro;
        for (; i + 8 <= re; i += 8) {
            int e0 = adj[i+0], e1 = adj[i+1], e2 = adj[i+2], e3 = adj[i+3];
            int e4 = adj[i+4], e5 = adj[i+5], e6 = adj[i+6], e7 = adj[i+7];
            u32 v0 = xp[(size_t)(g ? e1 : e0) * 32 + m];
            u32 v1 = xp[(size_t)(g ? e3 : e2) * 32 + m];
            u32 v2 = xp[(size_t)(g ? e5 : e4) * 32 + m];
            u32 v3 = xp[(size_t)(g ? e7 : e6) * 32 + m];
            ax0 += bflo(v0) + bflo(v1); ay0 += bfhi(v0) + bfhi(v1);
            ax1 += bflo(v2) + bflo(v3); ay1 += bfhi(v2) + bfhi(v3);
        }
        for (; i + 2 <= re; i += 2) {
            int e0 = adj[i], e1 = adj[i+1];
            u32 v = xp[(size_t)(g ? e1 : e0) * 32 + m];
            ax0 += bflo(v); ay0 += bfhi(v);
        }
        if (i < re) {                              // odd leftover edge
            u32 v = xp[(size_t)adj[i] * 32 + m];
            float wmask = (g == 0) ? 1.f : 0.f;
            ax0 += bflo(v) * wmask; ay0 += bfhi(v) * wmask;
        }
        float accx = ax0 + ax1, accy = ay0 + ay1;
        accx += __shfl_xor(accx, 32, 64);          // combine the two edge-halves
        accy += __shfl_xor(accy, 32, 64);
        float inv = 1.0f / fmaxf((float)deg, 1.0f);
        accx *= inv; accy *= inv;                  // lane m: mean features {2m, 2m+1}

        // concat-linear: feature 4k4+{0,1,2,3} = {x@2k4, y@2k4, x@2k4+1, y@2k4+1}
        float sum = bj;
        #pragma unroll
        for (int k4 = 0; k4 < 16; ++k4) {          // self half
            float4 w = Wt4[k4 * 64 + lane];
            sum = fmaf(bcastf(xvx, 2 * k4 + 0), w.x, sum);
            sum = fmaf(bcastf(xvy, 2 * k4 + 0), w.y, sum);
            sum = fmaf(bcastf(xvx, 2 * k4 + 1), w.z, sum);
            sum = fmaf(bcastf(xvy, 2 * k4 + 1), w.w, sum);
        }
        #pragma unroll
        for (int k4 = 0; k4 < 16; ++k4) {          // neighbor half
            float4 w = Wt4[(16 + k4) * 64 + lane];
            sum = fmaf(bcastf(accx, 2 * k4 + 0), w.x, sum);
            sum = fmaf(bcastf(accy, 2 * k4 + 0), w.y, sum);
            sum = fmaf(bcastf(accx, 2 * k4 + 1), w.z, sum);
            sum = fmaf(bcastf(accy, 2 * k4 + 1), w.w, sum);
        }
        float x2 = fmaxf(sum, 0.0f);   // ReLU; lane j holds output channel j

        if (!HEAD) {
            // pack pairs in-register; even lanes store 32 contiguous dwords/row
            u32 bits = f2bf(x2);
            u32 part = (u32)__shfl_xor((int)bits, 1, 64);
            if (!(lane & 1))
                ((u32*)out_)[(size_t)node * 32 + (lane >> 1)] = bits | (part << 16);
        } else {
            float h = bc1r;
            #pragma unroll
            for (int k2 = 0; k2 < 32; ++k2) {
                u32 wp = wc1p[k2 * 32 + l];
                h = fmaf(bcastf(x2, 2 * k2 + 0), bflo(wp), h);
                h = fmaf(bcastf(x2, 2 * k2 + 1), bfhi(wp), h);
            }
            h = fmaxf(h, 0.0f);
            float p0 = (lane < 32) ? h * w2a : 0.0f;
            float p1 = (lane < 32) ? h * w2b : 0.0f;
            #pragma unroll
            for (int off = 1; off < 64; off <<= 1) {
                p0 += __shfl_xor(p0, off, 64);
                p1 += __shfl_xor(p1, off, 64);
            }
            if (lane == 0) {
                float* outf = (float*)out_;
                outf[(size_t)node * 2 + 0] = p0 + bc20;
                outf[(size_t)node * 2 + 1] = p1 + bc21;
            }
        }
    }
}

extern "C" void kernel_launch(void* const* d_in, const int* in_sizes, int n_in,
                              void* d_out, int out_size, void* d_ws, size_t ws_size,
                              hipStream_t stream)
{
    const float* feat = (const float*)d_in[0];
    const int*   eidx = (const int*)d_in[1];
    const float* W1   = (const float*)d_in[2];
    const float* b1   = (const float*)d_in[3];
    const float* W2   = (const float*)d_in[4];
    const float* b2   = (const float*)d_in[5];
    const float* Wc1  = (const float*)d_in[6];
    const float* bc1  = (const float*)d_in[7];
    const float* Wc2  = (const float*)d_in[8];
    const float* bc2  = (const float*)d_in[9];

    int n = in_sizes[0] / D;    // 100000
    int E = in_sizes[1] / 2;    // 1600000
    const int* src = eidx;
    const int* dst = eidx + E;

    // workspace layout (words) ~33MB
    int* cnt      = (int*)d_ws;                 // [n]
    int* partials = cnt + n;                    // [128]
    int* blockoff = partials + 128;             // [128]
    int* rowptr   = blockoff + 128;             // [n+1]
    int* cursor   = rowptr + n + 1;             // [n]
    int* adj      = cursor + n;                 // [E]
    u32* featP    = (u32*)(adj + E);            // [n][32] packed bf16 pairs
    u32* x1P      = featP + (size_t)n * 32;     // [n][32]

    int nb = (n + TSCAN - 1) / TSCAN;           // 98

    // bf16 table + CSR build
    tobf16_kernel<<<2048, 256, 0, stream>>>(feat, featP, n * 32);
    hipMemsetAsync(cnt, 0, (size_t)n * sizeof(int), stream);
    hist_kernel<<<6250, 256, 0, stream>>>(dst, cnt, E);
    partial_kernel<<<nb, TSCAN, 0, stream>>>(cnt, partials, n);
    scanp_kernel<<<1, 128, 0, stream>>>(partials, blockoff, nb);
    rowptr_kernel<<<nb, TSCAN, 0, stream>>>(cnt, blockoff, rowptr, cursor, n);
    fill_kernel<<<6250, 256, 0, stream>>>(src, dst, cursor, adj, E);

    // R3's winning concurrency: 512 blocks x 512 threads (2 blocks/CU).
    // Layer 1: x1P = packbf16(relu(SAGE(featP)))
    sage_kernel<false><<<512, 512, 32768, stream>>>(
        featP, rowptr, adj, W1, b1,
        nullptr, nullptr, nullptr, nullptr, (void*)x1P, n);

    // Layer 2 + head: d_out = head(relu(SAGE(x1P)))
    sage_kernel<true><<<512, 512, 32768 + 4096, stream>>>(
        x1P, rowptr, adj, W2, b2,
        Wc1, bc1, Wc2, bc2, d_out, n);
}